// Round 11
// baseline (323.899 us; speedup 1.0000x reference)
//
#include <hip/hip_runtime.h>
#include <stdint.h>

#define DIM 768
#define NH 12
#define HD 64
#define BSZ 4
#define SEQ 2048
#define MROWS (BSZ*SEQ)   // 8192

typedef __attribute__((ext_vector_type(8))) short v8s;        // 8 bf16 (4 VGPRs)
typedef __attribute__((ext_vector_type(4))) float v4f;        // 4 fp32 acc
typedef __attribute__((ext_vector_type(8))) _Float16 v8h;     // 8 f16 (4 VGPRs)
typedef __attribute__((ext_vector_type(2))) __fp16 v2fp;      // cvt_pkrtz native type

__device__ __forceinline__ uint16_t f2bf(float x) {
  union { float f; uint32_t u; } v; v.f = x;
  uint32_t r = v.u + 0x7fffu + ((v.u >> 16) & 1u);   // RNE
  return (uint16_t)(r >> 16);
}

#if __has_builtin(__builtin_amdgcn_cvt_pk_bf16_f32)
typedef __attribute__((ext_vector_type(2))) __bf16 v2bf;
__device__ __forceinline__ uint32_t pack_bf16(float a, float b) {
  union { v2bf v; uint32_t u; } c;
  c.v = __builtin_amdgcn_cvt_pk_bf16_f32(a, b);
  return c.u;
}
#else
__device__ __forceinline__ uint32_t pack_bf16(float a, float b) {
  return (uint32_t)f2bf(a) | ((uint32_t)f2bf(b) << 16);
}
#endif

__device__ __forceinline__ uint32_t pack_f16(float a, float b) {
#if __has_builtin(__builtin_amdgcn_cvt_pkrtz)
  union { v2fp h; uint32_t u; } c;
  c.h = __builtin_amdgcn_cvt_pkrtz(a, b);
  return c.u;
#else
  union { _Float16 h[2]; uint32_t u; } c;
  c.h[0] = (_Float16)a; c.h[1] = (_Float16)b; return c.u;
#endif
}

__device__ __forceinline__ float fexp2(float x) {
#if __has_builtin(__builtin_amdgcn_exp2f)
  return __builtin_amdgcn_exp2f(x);
#else
  return exp2f(x);
#endif
}

// async global->LDS, 16B per lane; LDS dst = wave-uniform base + lane*16
__device__ __forceinline__ void gl16(const void* g, void* l) {
  __builtin_amdgcn_global_load_lds(
      (const __attribute__((address_space(1))) unsigned int*)g,
      (__attribute__((address_space(3))) unsigned int*)l, 16, 0, 0);
}

// vmcnt(0)-drain + raw barrier pair, placed AFTER compute (2-phase pipeline)
__device__ __forceinline__ void pipe_sync() {
  asm volatile("s_waitcnt vmcnt(0)" ::: "memory");
  __builtin_amdgcn_s_barrier();
  __builtin_amdgcn_sched_barrier(0);   // keep next tile's ds_reads below barrier
}

// ------- fused pre-pass: cvt_bf16 + wtrans + mask_bits (ONE launch) ------------
// Block-range partition.  All three sections are streaming/memory-bound with no
// LDS-residency or long-serial-wave conflicts, so they overlap cleanly at HBM.
#define CVT_BLKS  12288   // 2 * MROWS*DIM/4 / 256
#define WT_BLKS   2304    // 4 * 24 * 24
#define MASK_BLKS 65536   // BSZ*32*SEQ words, 1 word per wave, 4 waves/block
__global__ __launch_bounds__(256) void prepass_kernel(
    const float* __restrict__ from_t, const float* __restrict__ to_t,
    uint16_t* __restrict__ Xf, uint16_t* __restrict__ Xt,
    const float* __restrict__ Wq, const float* __restrict__ Wk,
    const float* __restrict__ Wv, const float* __restrict__ Wo,
    uint16_t* __restrict__ WT,
    const int* __restrict__ maski, unsigned long long* __restrict__ Mbits)
{
  __shared__ float tile[32][33];
  int blk = blockIdx.x, tid = threadIdx.x;
  if (blk < CVT_BLKS) {
    // fp32 -> bf16, both X tensors
    int n4 = MROWS * DIM / 4;
    int i = blk * 256 + tid;
    const float* src = (i < n4) ? from_t : to_t;
    uint16_t* dst = (i < n4) ? Xf : Xt;
    int j = (i < n4) ? i : i - n4;
    float4 v = ((const float4*)src)[j];
    uint2 o;
    o.x = pack_bf16(v.x, v.y);
    o.y = pack_bf16(v.z, v.w);
    ((uint2*)dst)[j] = o;
  } else if (blk < CVT_BLKS + WT_BLKS) {
    // W [K][N] fp32 -> WT [N][K] bf16
    int r = blk - CVT_BLKS;
    int z = r / 576, rem = r - z * 576;
    int by = rem / 24, bx = rem - by * 24;
    const float* src = (z==0) ? Wq : (z==1) ? Wk : (z==2) ? Wv : Wo;
    uint16_t* dst = WT + (size_t)z * DIM * DIM;
    int tx = tid & 31, ty = tid >> 5;
    int x  = bx * 32 + tx;
    int y0 = by * 32;
    for (int jj = ty; jj < 32; jj += 8)
      tile[jj][tx] = src[(size_t)(y0 + jj) * DIM + x];
    __syncthreads();
    int xo = y0 + tx;
    for (int jj = ty; jj < 32; jj += 8)
      dst[(size_t)(bx * 32 + jj) * DIM + xo] = f2bf(tile[tx][jj]);
  } else {
    // mask int32 -> u64 bitmask [b][kt][q]; 1 word per wave
    int gtid = (blk - CVT_BLKS - WT_BLKS) * 256 + tid;
    int w = gtid >> 6;
    int lane = tid & 63;
    int b  = w >> 16;
    int q  = (w >> 5) & 2047;
    int kt = w & 31;
    int m = maski[((size_t)b * SEQ + q) * SEQ + kt * 64 + lane];
    unsigned long long bits = __ballot(m != 0);
    if (lane == 0) Mbits[((size_t)b * 32 + kt) * SEQ + q] = bits;
  }
}

// ---------------- GEMM (2-phase pipelined DMA staging): C = A(bf16)@WT^T + bias -
// Round-7 body.  QKV is now SPLIT into two launches by A-tensor to fit per-XCD
// L2: XCD = blockIdx.x%8, so co-resident blocks pin 8 A-panels + their W's.
// Combined QKV launch held Xf(1.6) + Xt(1.6) + 3W(3.5) = 6.6 MB > 4 MB L2 ->
// A-staging missed to HBM (~900cy) under the per-iter vmcnt(0) drain.
// Split: Q-launch 2.8 MB, KV-launch 3.9 MB — both fit.
// mode 0: Q -> Qw [b,h,s,d]*(SCALE*log2e)  mode 1: K -> Kw (d-chunk swz by s&7)
// mode 2: V -> Vw [b,h,d,s] f16, kk pair-permuted + chunk swz by d&7
// mode 3: O -> d_out fp32 [m,n]
__global__ __launch_bounds__(256) void gemm_kernel(
    const uint16_t* __restrict__ Xf, const uint16_t* __restrict__ Xt,
    const uint16_t* __restrict__ WT, const uint16_t* __restrict__ AO,
    const float* __restrict__ bq, const float* __restrict__ bk,
    const float* __restrict__ bv, const float* __restrict__ bo,
    uint16_t* __restrict__ Qw, uint16_t* __restrict__ Kw, uint16_t* __restrict__ Vw,
    float* __restrict__ Out, int mode_base)
{
  __shared__ alignas(16) uint16_t As[2][128 * 32];
  __shared__ alignas(16) uint16_t Bs[2][128 * 32];
  int mode = mode_base + blockIdx.z;
  const uint16_t* A = (mode == 0) ? Xf : (mode == 3 ? AO : Xt);
  const uint16_t* W = WT + (size_t)mode * DIM * DIM;
  const float* bias = (mode == 0) ? bq : (mode == 1) ? bk : (mode == 2) ? bv : bo;

  int m0 = blockIdx.x * 128, n0 = blockIdx.y * 128;
  int tid = threadIdx.x;
  int wave = tid >> 6, lane = tid & 63, lr = lane & 15, quad = lane >> 4;
  int wm = (wave >> 1) * 64, wn = (wave & 1) * 64;

  int seg = (lane & 3) ^ ((lane >> 3) & 3);
  const uint16_t* agl = A + (size_t)(m0 + wave * 32 + (lane >> 2)) * DIM + seg * 8;
  const uint16_t* bgl = W + (size_t)(n0 + wave * 32 + (lane >> 2)) * DIM + seg * 8;
  int lb = wave * 1024;             // uint16 idx; second call adds 512
  int ck = (lr >> 1) & 3;

  v4f acc[4][4];
  v4f vz = {0.f, 0.f, 0.f, 0.f};
  #pragma unroll
  for (int i = 0; i < 4; i++)
    #pragma unroll
    for (int j = 0; j < 4; j++) acc[i][j] = vz;

  // prologue: stage k0=0 into buf 0
  gl16(agl,            &As[0][lb]);
  gl16(agl + 16 * DIM, &As[0][lb + 512]);
  gl16(bgl,            &Bs[0][lb]);
  gl16(bgl + 16 * DIM, &Bs[0][lb + 512]);
  pipe_sync();

  int cur = 0;
  const int NT = DIM / 32;   // 24
  for (int t = 0; t < NT; ++t) {
    if (t + 1 < NT) {
      int kn = (t + 1) * 32;
      gl16(agl + kn,            &As[cur ^ 1][lb]);
      gl16(agl + kn + 16 * DIM, &As[cur ^ 1][lb + 512]);
      gl16(bgl + kn,            &Bs[cur ^ 1][lb]);
      gl16(bgl + kn + 16 * DIM, &Bs[cur ^ 1][lb + 512]);
    }
    v8s af[4], bfr[4];
    #pragma unroll
    for (int i = 0; i < 4; i++)
      af[i] = *(const v8s*)&As[cur][(wm + i * 16 + lr) * 32 + ((quad ^ ck) << 3)];
    #pragma unroll
    for (int j = 0; j < 4; j++)
      bfr[j] = *(const v8s*)&Bs[cur][(wn + j * 16 + lr) * 32 + ((quad ^ ck) << 3)];
    #pragma unroll
    for (int i = 0; i < 4; i++)
      #pragma unroll
      for (int j = 0; j < 4; j++)
        acc[i][j] = __builtin_amdgcn_mfma_f32_16x16x32_bf16(af[i], bfr[j], acc[i][j], 0, 0, 0);
    if (t + 1 < NT) pipe_sync();
    cur ^= 1;
  }

  float bj[4];
  #pragma unroll
  for (int j = 0; j < 4; j++) bj[j] = bias[n0 + wn + j * 16 + lr];

  if (mode == 3) {
    #pragma unroll
    for (int i = 0; i < 4; i++) {
      int m = m0 + wm + i * 16 + quad * 4;
      #pragma unroll
      for (int j = 0; j < 4; j++) {
        int n = n0 + wn + j * 16 + lr;
        #pragma unroll
        for (int r = 0; r < 4; r++)
          Out[(size_t)(m + r) * DIM + n] = acc[i][j][r] + bj[j];
      }
    }
  } else if (mode == 2) {
    // Vw f16 [b,h,d,s]: within each 64-kk group, pos = pair*32+quadk*8+(nt&1)*4+j,
    // then 16B-chunk XOR-swizzled by d&7.  (kk = s&63; j==r since s0 is 4-aligned.)
    #pragma unroll
    for (int i = 0; i < 4; i++) {
      int m = m0 + wm + i * 16 + quad * 4;
      int b = m >> 11, s0 = m & 2047;
      int kk0 = s0 & 63;
      int pos = (kk0 >> 5) * 32 + ((kk0 >> 2) & 3) * 8 + ((kk0 >> 4) & 1) * 4;
      int chunk = pos >> 3, off = pos & 7;
      #pragma unroll
      for (int j = 0; j < 4; j++) {
        int n = n0 + wn + j * 16 + lr;
        int h = n >> 6, d = n & 63;
        uint2 pk;
        pk.x = pack_f16(acc[i][j][0] + bj[j], acc[i][j][1] + bj[j]);
        pk.y = pack_f16(acc[i][j][2] + bj[j], acc[i][j][3] + bj[j]);
        int idx = (s0 & ~63) + ((chunk ^ (d & 7)) << 3) + off;
        *(uint2*)&Vw[((size_t)(b * NH + h) * HD + d) * SEQ + idx] = pk;
      }
    }
  } else {
    uint16_t* Dst = (mode == 0) ? Qw : Kw;
    float scale = (mode == 0) ? 0.18033688f : 1.0f;   // HD^-0.5 * log2(e) folded into Q
    #pragma unroll
    for (int i = 0; i < 4; i++) {
      int m = m0 + wm + i * 16 + quad * 4;
      int b = m >> 11, s0 = m & 2047;
      #pragma unroll
      for (int j = 0; j < 4; j++) {
        int n = n0 + wn + j * 16 + lr;
        int h = n >> 6, d = n & 63;
        #pragma unroll
        for (int r = 0; r < 4; r++) {
          float v = (acc[i][j][r] + bj[j]) * scale;
          int s = s0 + r;
          int dd = (mode == 1) ? ((((d >> 3) ^ (s & 7)) << 3) + (d & 7)) : d;
          Dst[((size_t)(b * NH + h) * SEQ + s) * HD + dd] = f2bf(v);
        }
      }
    }
  }
}

// ---------------- flash attention: 4 waves x 32 q/wave, 128-q block, 2-phase ----
// Round-10 body (81 µs): q-group-shared K/V frags, T5 setprio on MFMA clusters.
__global__ __launch_bounds__(256, 3) void flash_kernel(
    const uint16_t* __restrict__ Qg, const uint16_t* __restrict__ Kg,
    const uint16_t* __restrict__ Vg, const unsigned long long* __restrict__ Mb,
    uint16_t* __restrict__ AO)
{
  __shared__ alignas(16) uint16_t Ks[2][64 * 64];   // 2 x 8 KB, swizzle baked in Kw
  __shared__ alignas(16) uint16_t Vs[2][64 * 64];   // 2 x 8 KB f16, baked in Vw

  int tid = threadIdx.x, wave = tid >> 6, lane = tid & 63, lr = lane & 15, quad = lane >> 4;

  // XCD swizzle: dispatch id d -> XCD d&7 (round-robin).  768 = 8 * 96.
  int d = blockIdx.x + (blockIdx.y << 4);
  int nid = (d & 7) * 96 + (d >> 3);
  int bh = nid >> 4;
  int q0 = (nid & 15) * 128;
  int b = bh / NH, h = bh - b * NH;

  const uint16_t* Qp = Qg + (size_t)bh * SEQ * HD;
  const uint16_t* Kp = Kg + (size_t)bh * SEQ * HD;
  const uint16_t* Vp = Vg + (size_t)bh * HD * SEQ;
  int qg0 = q0 + wave * 32 + lr;
  int qg1 = qg0 + 16;
  const unsigned long long* Mp0 = Mb + (size_t)b * 32 * SEQ + qg0;
  const unsigned long long* Mp1 = Mp0 + 16;

  int swk = lr & 7, sh0 = quad * 4;

  v8s qf0a = *(const v8s*)&Qp[(size_t)qg0 * HD + quad * 8];
  v8s qf0b = *(const v8s*)&Qp[(size_t)qg0 * HD + 32 + quad * 8];
  v8s qf1a = *(const v8s*)&Qp[(size_t)qg1 * HD + quad * 8];
  v8s qf1b = *(const v8s*)&Qp[(size_t)qg1 * HD + 32 + quad * 8];

  // DMA: 4 waves x 4 calls x 64 lanes x 16B = 16 KB per tile (K 8KB + V 8KB);
  // wave w stages K rows [16w,16w+16) and V rows [16w,16w+16).
  const uint16_t* kgl = Kp + ((size_t)(wave * 16 + (lane >> 3)) * HD + (lane & 7) * 8);
  const uint16_t* vgl = Vp + ((size_t)(wave * 16 + (lane >> 3)) * SEQ + (lane & 7) * 8);
  int lb = wave * 1024;   // uint16 idx: 16 rows x 64 elems per wave

  v8h ones;
  #pragma unroll
  for (int i = 0; i < 8; i++) ones[i] = (_Float16)1.0f;

  v4f acc0[4], acc1[4], lacc0, lacc1;
  v4f vz = {0.f, 0.f, 0.f, 0.f};
  v4f m8 = {-8.f, -8.f, -8.f, -8.f};
  #pragma unroll
  for (int dt = 0; dt < 4; dt++) { acc0[dt] = vz; acc1[dt] = vz; }
  lacc0 = vz; lacc1 = vz;

  // prologue: stage tile 0 into buf 0, fetch its mask words
  gl16(kgl,                   &Ks[0][lb]);
  gl16(kgl + (size_t)8 * HD,  &Ks[0][lb + 512]);
  gl16(vgl,                   &Vs[0][lb]);
  gl16(vgl + (size_t)8 * SEQ, &Vs[0][lb + 512]);
  unsigned long long mw0_cur = Mp0[0];
  unsigned long long mw1_cur = Mp1[0];
  __syncthreads();

  int cur = 0;
  const int NT = SEQ / 64;   // 32
  for (int it = 0; it < NT; ++it) {
    unsigned long long mw0_next = 0, mw1_next = 0;
    if (it + 1 < NT) {
      int kn = (it + 1) * 64;
      gl16(kgl + (size_t)kn * HD,       &Ks[cur ^ 1][lb]);
      gl16(kgl + (size_t)(kn + 8) * HD, &Ks[cur ^ 1][lb + 512]);
      gl16(vgl + kn,                    &Vs[cur ^ 1][lb]);
      gl16(vgl + kn + (size_t)8 * SEQ,  &Vs[cur ^ 1][lb + 512]);
      mw0_next = Mp0[(size_t)(it + 1) * SEQ];
      mw1_next = Mp1[(size_t)(it + 1) * SEQ];
    }

    uint32_t m0lo = (uint32_t)mw0_cur, m0hi = (uint32_t)(mw0_cur >> 32);
    uint32_t m1lo = (uint32_t)mw1_cur, m1hi = (uint32_t)(mw1_cur >> 32);
    v8h pf0[2], pf1[2];
    #pragma unroll
    for (int p = 0; p < 2; p++) {
      v4f sA0 = m8, sB0 = m8, sA1 = m8, sB1 = m8;
      __builtin_amdgcn_s_setprio(1);
      {
        int rowb = ((2 * p) * 16 + lr) << 6;
        v8s kf0 = *(const v8s*)&Ks[cur][rowb + ((quad ^ swk) << 3)];
        v8s kf1 = *(const v8s*)&Ks[cur][rowb + (((quad + 4) ^ swk) << 3)];
        sA0 = __builtin_amdgcn_mfma_f32_16x16x32_bf16(kf0, qf0a, sA0, 0, 0, 0);
        sA0 = __builtin_amdgcn_mfma_f32_16x16x32_bf16(kf1, qf0b, sA0, 0, 0, 0);
        sA1 = __builtin_amdgcn_mfma_f32_16x16x32_bf16(kf0, qf1a, sA1, 0, 0, 0);
        sA1 = __builtin_amdgcn_mfma_f32_16x16x32_bf16(kf1, qf1b, sA1, 0, 0, 0);
      }
      {
        int rowb = ((2 * p + 1) * 16 + lr) << 6;
        v8s kf0 = *(const v8s*)&Ks[cur][rowb + ((quad ^ swk) << 3)];
        v8s kf1 = *(const v8s*)&Ks[cur][rowb + (((quad + 4) ^ swk) << 3)];
        sB0 = __builtin_amdgcn_mfma_f32_16x16x32_bf16(kf0, qf0a, sB0, 0, 0, 0);
        sB0 = __builtin_amdgcn_mfma_f32_16x16x32_bf16(kf1, qf0b, sB0, 0, 0, 0);
        sB1 = __builtin_amdgcn_mfma_f32_16x16x32_bf16(kf0, qf1a, sB1, 0, 0, 0);
        sB1 = __builtin_amdgcn_mfma_f32_16x16x32_bf16(kf1, qf1b, sB1, 0, 0, 0);
      }
      __builtin_amdgcn_s_setprio(0);
      // softmax for both q-groups, this p (4+4 elements each)
      uint32_t w0 = p ? m0hi : m0lo, w1 = p ? m1hi : m1lo;
      uint32_t a0 = (w0 >> sh0) & 15u, b0 = (w0 >> (sh0 + 16)) & 15u;
      uint32_t a1 = (w1 >> sh0) & 15u, b1 = (w1 >> (sh0 + 16)) & 15u;
      float p0[8], p1[8];
      #pragma unroll
      for (int r = 0; r < 4; r++) {
        float e0a = fexp2(sA0[r]), e0b = fexp2(sB0[r]);
        float e1a = fexp2(sA1[r]), e1b = fexp2(sB1[r]);
        p0[r]     = (a0 & (1u << r)) ? e0a : 0.0f;
        p0[4 + r] = (b0 & (1u << r)) ? e0b : 0.0f;
        p1[r]     = (a1 & (1u << r)) ? e1a : 0.0f;
        p1[4 + r] = (b1 & (1u << r)) ? e1b : 0.0f;
      }
      union { uint4 u; v8h h; } c0, c1;
      c0.u.x = pack_f16(p0[0], p0[1]); c0.u.y = pack_f16(p0[2], p0[3]);
      c0.u.z = pack_f16(p0[4], p0[5]); c0.u.w = pack_f16(p0[6], p0[7]);
      c1.u.x = pack_f16(p1[0], p1[1]); c1.u.y = pack_f16(p1[2], p1[3]);
      c1.u.z = pack_f16(p1[4], p1[5]); c1.u.w = pack_f16(p1[6], p1[7]);
      pf0[p] = c0.h;
      pf1[p] = c1.h;
    }

    // O^T += V^T.P^T : one b128 A-frag per (dt, pair), shared across q-groups
    __builtin_amdgcn_s_setprio(1);
    #pragma unroll
    for (int dt = 0; dt < 4; dt++) {
      int rowb = (dt * 16 + lr) << 6;
      #pragma unroll
      for (int p = 0; p < 2; p++) {
        v8h vv = *(const v8h*)&Vs[cur][rowb + (((p * 4 + quad) ^ swk) << 3)];
        acc0[dt] = __builtin_amdgcn_mfma_f32_16x16x32_f16(vv, pf0[p], acc0[dt], 0, 0, 0);
        acc1[dt] = __builtin_amdgcn_mfma_f32_16x16x32_f16(vv, pf1[p], acc1[dt], 0, 0, 0);
      }
    }
    // row-sum of P via ones-A MFMA: every lane gets full sum (all rows equal)
    lacc0 = __builtin_amdgcn_mfma_f32_16x16x32_f16(ones, pf0[0], lacc0, 0, 0, 0);
    lacc0 = __builtin_amdgcn_mfma_f32_16x16x32_f16(ones, pf0[1], lacc0, 0, 0, 0);
    lacc1 = __builtin_amdgcn_mfma_f32_16x16x32_f16(ones, pf1[0], lacc1, 0, 0, 0);
    lacc1 = __builtin_amdgcn_mfma_f32_16x16x32_f16(ones, pf1[1], lacc1, 0, 0, 0);
    __builtin_amdgcn_s_setprio(0);

    __syncthreads();     // drains this wave's DMA (vmcnt) late, then barrier
    mw0_cur = mw0_next;
    mw1_cur = mw1_next;
    cur ^= 1;
  }

  float ri0 = 1.0f / lacc0[0];
  float ri1 = 1.0f / lacc1[0];

  #pragma unroll
  for (int dt = 0; dt < 4; dt++) {
    uint2 pk;
    pk.x = pack_bf16(acc0[dt][0] * ri0, acc0[dt][1] * ri0);
    pk.y = pack_bf16(acc0[dt][2] * ri0, acc0[dt][3] * ri0);
    *(uint2*)&AO[(size_t)(b * SEQ + qg0) * DIM + h * HD + dt * 16 + sh0] = pk;
    pk.x = pack_bf16(acc1[dt][0] * ri1, acc1[dt][1] * ri1);
    pk.y = pack_bf16(acc1[dt][2] * ri1, acc1[dt][3] * ri1);
    *(uint2*)&AO[(size_t)(b * SEQ + qg1) * DIM + h * HD + dt * 16 + sh0] = pk;
  }
}

// ---------------- launch ----------------
extern "C" void kernel_launch(void* const* d_in, const int* in_sizes, int n_in,
                              void* d_out, int out_size, void* d_ws, size_t ws_size,
                              hipStream_t stream) {
  const float* from_t = (const float*)d_in[0];
  const float* to_t   = (const float*)d_in[1];
  const int*   maski  = (const int*)d_in[2];
  const float* Wq = (const float*)d_in[3];  const float* bq = (const float*)d_in[4];
  const float* Wk = (const float*)d_in[5];  const float* bk = (const float*)d_in[6];
  const float* Wv = (const float*)d_in[7];  const float* bv = (const float*)d_in[8];
  const float* Wo = (const float*)d_in[9];  const float* bo = (const float*)d_in[10];

  char* ws = (char*)d_ws;
  size_t off = 0;
  uint16_t* Xf = (uint16_t*)(ws + off); off += (size_t)MROWS * DIM * 2;
  uint16_t* Xt = (uint16_t*)(ws + off); off += (size_t)MROWS * DIM * 2;
  uint16_t* WT = (uint16_t*)(ws + off); off += (size_t)4 * DIM * DIM * 2;
  unsigned long long* Mbits = (unsigned long long*)(ws + off);
  off += (size_t)BSZ * 32 * SEQ * 8;                                    // 2 MB
  uint16_t* Qw = (uint16_t*)(ws + off); off += (size_t)MROWS * DIM * 2; // [b,h,s,d] bf16
  uint16_t* Kw = (uint16_t*)(ws + off); off += (size_t)MROWS * DIM * 2; // [b,h,s,d] bf16 swz
  uint16_t* Vw = (uint16_t*)(ws + off); off += (size_t)MROWS * DIM * 2; // [b,h,d,s] f16 perm+swz
  uint16_t* AO = (uint16_t*)(ws + off); off += (size_t)MROWS * DIM * 2; // [m,768] bf16
  float* Out = (float*)d_out;

  prepass_kernel<<<CVT_BLKS + WT_BLKS + MASK_BLKS, 256, 0, stream>>>(
      from_t, to_t, Xf, Xt, Wq, Wk, Wv, Wo, WT, maski, Mbits);

  // QKV split by A-tensor for per-XCD L2 fit: Q (Xf) alone, then K+V (Xt).
  gemm_kernel<<<dim3(64, 6, 1), 256, 0, stream>>>(Xf, Xt, WT, AO, bq, bk, bv, bo,
                                                  Qw, Kw, Vw, Out, 0);
  gemm_kernel<<<dim3(64, 6, 2), 256, 0, stream>>>(Xf, Xt, WT, AO, bq, bk, bv, bo,
                                                  Qw, Kw, Vw, Out, 1);
  flash_kernel<<<dim3(SEQ / 128, BSZ * NH), 256, 0, stream>>>(Qw, Kw, Vw, Mbits, AO);
  gemm_kernel<<<dim3(64, 6, 1), 256, 0, stream>>>(Xf, Xt, WT, AO, bq, bk, bv, bo,
                                                  Qw, Kw, Vw, Out, 3);
}

// Round 12
// 305.251 us; speedup vs baseline: 1.0611x; 1.0611x over previous
//
#include <hip/hip_runtime.h>
#include <stdint.h>

#define DIM 768
#define NH 12
#define HD 64
#define BSZ 4
#define SEQ 2048
#define MROWS (BSZ*SEQ)   // 8192

typedef __attribute__((ext_vector_type(8))) short v8s;        // 8 bf16 (4 VGPRs)
typedef __attribute__((ext_vector_type(4))) float v4f;        // 4 fp32 acc
typedef __attribute__((ext_vector_type(8))) _Float16 v8h;     // 8 f16 (4 VGPRs)
typedef __attribute__((ext_vector_type(2))) __fp16 v2fp;      // cvt_pkrtz native type

__device__ __forceinline__ uint16_t f2bf(float x) {
  union { float f; uint32_t u; } v; v.f = x;
  uint32_t r = v.u + 0x7fffu + ((v.u >> 16) & 1u);   // RNE
  return (uint16_t)(r >> 16);
}

#if __has_builtin(__builtin_amdgcn_cvt_pk_bf16_f32)
typedef __attribute__((ext_vector_type(2))) __bf16 v2bf;
__device__ __forceinline__ uint32_t pack_bf16(float a, float b) {
  union { v2bf v; uint32_t u; } c;
  c.v = __builtin_amdgcn_cvt_pk_bf16_f32(a, b);
  return c.u;
}
#else
__device__ __forceinline__ uint32_t pack_bf16(float a, float b) {
  return (uint32_t)f2bf(a) | ((uint32_t)f2bf(b) << 16);
}
#endif

__device__ __forceinline__ uint32_t pack_f16(float a, float b) {
#if __has_builtin(__builtin_amdgcn_cvt_pkrtz)
  union { v2fp h; uint32_t u; } c;
  c.h = __builtin_amdgcn_cvt_pkrtz(a, b);
  return c.u;
#else
  union { _Float16 h[2]; uint32_t u; } c;
  c.h[0] = (_Float16)a; c.h[1] = (_Float16)b; return c.u;
#endif
}

__device__ __forceinline__ float fexp2(float x) {
#if __has_builtin(__builtin_amdgcn_exp2f)
  return __builtin_amdgcn_exp2f(x);
#else
  return exp2f(x);
#endif
}

// bit-spread: 16-bit c -> 64-bit with bit i of c at position 4i
__device__ __forceinline__ unsigned long long spread4(uint32_t c) {
  unsigned long long x = c & 0xFFFFu;
  x = (x | (x << 24)) & 0x000000FF000000FFull;
  x = (x | (x << 12)) & 0x000F000F000F000Full;
  x = (x | (x << 6))  & 0x0303030303030303ull;
  x = (x | (x << 3))  & 0x1111111111111111ull;
  return x;
}

// async global->LDS, 16B per lane; LDS dst = wave-uniform base + lane*16
__device__ __forceinline__ void gl16(const void* g, void* l) {
  __builtin_amdgcn_global_load_lds(
      (const __attribute__((address_space(1))) unsigned int*)g,
      (__attribute__((address_space(3))) unsigned int*)l, 16, 0, 0);
}

// vmcnt(0)-drain + raw barrier pair, placed AFTER compute (2-phase pipeline)
__device__ __forceinline__ void pipe_sync() {
  asm volatile("s_waitcnt vmcnt(0)" ::: "memory");
  __builtin_amdgcn_s_barrier();
  __builtin_amdgcn_sched_barrier(0);   // keep next tile's ds_reads below barrier
}

// ------- fused pre-pass: cvt_bf16 + wtrans + mask_bits (ONE launch) ------------
// Block-range partition; all three sections streaming/memory-bound, overlap at
// HBM.  Mask section int4-vectorized (16B/lane, 1 KB/wave = 4 kt-words): four
// ballots + 16->64 bit-spread assemble each 16-lane group's u64 word, replacing
// the previous 4B/lane scalar loads (G13: scalar loads are the weak BW shape).
#define CVT_BLKS  12288   // 2 * MROWS*DIM/4 / 256
#define WT_BLKS   2304    // 4 * 24 * 24
#define MASK_BLKS 16384   // 65536 groups (4 kt-words each) / 4 waves-per-block
__global__ __launch_bounds__(256) void prepass_kernel(
    const float* __restrict__ from_t, const float* __restrict__ to_t,
    uint16_t* __restrict__ Xf, uint16_t* __restrict__ Xt,
    const float* __restrict__ Wq, const float* __restrict__ Wk,
    const float* __restrict__ Wv, const float* __restrict__ Wo,
    uint16_t* __restrict__ WT,
    const int* __restrict__ maski, unsigned long long* __restrict__ Mbits)
{
  __shared__ float tile[32][33];
  int blk = blockIdx.x, tid = threadIdx.x;
  if (blk < CVT_BLKS) {
    // fp32 -> bf16, both X tensors
    int n4 = MROWS * DIM / 4;
    int i = blk * 256 + tid;
    const float* src = (i < n4) ? from_t : to_t;
    uint16_t* dst = (i < n4) ? Xf : Xt;
    int j = (i < n4) ? i : i - n4;
    float4 v = ((const float4*)src)[j];
    uint2 o;
    o.x = pack_bf16(v.x, v.y);
    o.y = pack_bf16(v.z, v.w);
    ((uint2*)dst)[j] = o;
  } else if (blk < CVT_BLKS + WT_BLKS) {
    // W [K][N] fp32 -> WT [N][K] bf16
    int r = blk - CVT_BLKS;
    int z = r / 576, rem = r - z * 576;
    int by = rem / 24, bx = rem - by * 24;
    const float* src = (z==0) ? Wq : (z==1) ? Wk : (z==2) ? Wv : Wo;
    uint16_t* dst = WT + (size_t)z * DIM * DIM;
    int tx = tid & 31, ty = tid >> 5;
    int x  = bx * 32 + tx;
    int y0 = by * 32;
    for (int jj = ty; jj < 32; jj += 8)
      tile[jj][tx] = src[(size_t)(y0 + jj) * DIM + x];
    __syncthreads();
    int xo = y0 + tx;
    for (int jj = ty; jj < 32; jj += 8)
      dst[(size_t)(bx * 32 + jj) * DIM + xo] = f2bf(tile[tx][jj]);
  } else {
    // mask int32 -> u64 bitmask [b][kt][q], 1 KB contiguous per wave.
    // Group g: b=g>>14, q=(g>>3)&2047, ktbase=(g&7)*4.  Lane L reads int4 at
    // base + (L>>4)*64 + (L&15)*4 -> wave covers 256 consecutive ints.
    // Quad qd owns word kt=ktbase+qd; bit 4i+j = lane(16qd+i) elem j.
    int gtid = (blk - CVT_BLKS - WT_BLKS) * 256 + tid;
    int g = gtid >> 6;
    int lane = tid & 63;
    int b   = g >> 14;
    int q   = (g >> 3) & 2047;
    int ktb = (g & 7) * 4;
    size_t base = ((size_t)b * SEQ + q) * SEQ + (size_t)ktb * 64;
    int4 m = *(const int4*)&maski[base + (lane >> 4) * 64 + (lane & 15) * 4];
    unsigned long long b0 = __ballot(m.x != 0);
    unsigned long long b1 = __ballot(m.y != 0);
    unsigned long long b2 = __ballot(m.z != 0);
    unsigned long long b3 = __ballot(m.w != 0);
    int qd = lane >> 4, sh = qd * 16;
    unsigned long long word =  spread4((uint32_t)(b0 >> sh))
                            | (spread4((uint32_t)(b1 >> sh)) << 1)
                            | (spread4((uint32_t)(b2 >> sh)) << 2)
                            | (spread4((uint32_t)(b3 >> sh)) << 3);
    if ((lane & 15) == 0)
      Mbits[((size_t)b * 32 + ktb + qd) * SEQ + q] = word;
  }
}

// ---------------- GEMM (2-phase pipelined DMA staging): C = A(bf16)@WT^T + bias -
// Round-7 body, combined QKV launch restored (round-11 L2-split refuted: cost a
// launch gap, no L2 benefit).
// mode 0: Q -> Qw [b,h,s,d]*(SCALE*log2e)  mode 1: K -> Kw (d-chunk swz by s&7)
// mode 2: V -> Vw [b,h,d,s] f16, kk pair-permuted + chunk swz by d&7
// mode 3: O -> d_out fp32 [m,n]
__global__ __launch_bounds__(256) void gemm_kernel(
    const uint16_t* __restrict__ Xf, const uint16_t* __restrict__ Xt,
    const uint16_t* __restrict__ WT, const uint16_t* __restrict__ AO,
    const float* __restrict__ bq, const float* __restrict__ bk,
    const float* __restrict__ bv, const float* __restrict__ bo,
    uint16_t* __restrict__ Qw, uint16_t* __restrict__ Kw, uint16_t* __restrict__ Vw,
    float* __restrict__ Out, int mode_base)
{
  __shared__ alignas(16) uint16_t As[2][128 * 32];
  __shared__ alignas(16) uint16_t Bs[2][128 * 32];
  int mode = mode_base + blockIdx.z;
  const uint16_t* A = (mode == 0) ? Xf : (mode == 3 ? AO : Xt);
  const uint16_t* W = WT + (size_t)mode * DIM * DIM;
  const float* bias = (mode == 0) ? bq : (mode == 1) ? bk : (mode == 2) ? bv : bo;

  int m0 = blockIdx.x * 128, n0 = blockIdx.y * 128;
  int tid = threadIdx.x;
  int wave = tid >> 6, lane = tid & 63, lr = lane & 15, quad = lane >> 4;
  int wm = (wave >> 1) * 64, wn = (wave & 1) * 64;

  int seg = (lane & 3) ^ ((lane >> 3) & 3);
  const uint16_t* agl = A + (size_t)(m0 + wave * 32 + (lane >> 2)) * DIM + seg * 8;
  const uint16_t* bgl = W + (size_t)(n0 + wave * 32 + (lane >> 2)) * DIM + seg * 8;
  int lb = wave * 1024;             // uint16 idx; second call adds 512
  int ck = (lr >> 1) & 3;

  v4f acc[4][4];
  v4f vz = {0.f, 0.f, 0.f, 0.f};
  #pragma unroll
  for (int i = 0; i < 4; i++)
    #pragma unroll
    for (int j = 0; j < 4; j++) acc[i][j] = vz;

  // prologue: stage k0=0 into buf 0
  gl16(agl,            &As[0][lb]);
  gl16(agl + 16 * DIM, &As[0][lb + 512]);
  gl16(bgl,            &Bs[0][lb]);
  gl16(bgl + 16 * DIM, &Bs[0][lb + 512]);
  pipe_sync();

  int cur = 0;
  const int NT = DIM / 32;   // 24
  for (int t = 0; t < NT; ++t) {
    if (t + 1 < NT) {
      int kn = (t + 1) * 32;
      gl16(agl + kn,            &As[cur ^ 1][lb]);
      gl16(agl + kn + 16 * DIM, &As[cur ^ 1][lb + 512]);
      gl16(bgl + kn,            &Bs[cur ^ 1][lb]);
      gl16(bgl + kn + 16 * DIM, &Bs[cur ^ 1][lb + 512]);
    }
    v8s af[4], bfr[4];
    #pragma unroll
    for (int i = 0; i < 4; i++)
      af[i] = *(const v8s*)&As[cur][(wm + i * 16 + lr) * 32 + ((quad ^ ck) << 3)];
    #pragma unroll
    for (int j = 0; j < 4; j++)
      bfr[j] = *(const v8s*)&Bs[cur][(wn + j * 16 + lr) * 32 + ((quad ^ ck) << 3)];
    #pragma unroll
    for (int i = 0; i < 4; i++)
      #pragma unroll
      for (int j = 0; j < 4; j++)
        acc[i][j] = __builtin_amdgcn_mfma_f32_16x16x32_bf16(af[i], bfr[j], acc[i][j], 0, 0, 0);
    if (t + 1 < NT) pipe_sync();
    cur ^= 1;
  }

  float bj[4];
  #pragma unroll
  for (int j = 0; j < 4; j++) bj[j] = bias[n0 + wn + j * 16 + lr];

  if (mode == 3) {
    #pragma unroll
    for (int i = 0; i < 4; i++) {
      int m = m0 + wm + i * 16 + quad * 4;
      #pragma unroll
      for (int j = 0; j < 4; j++) {
        int n = n0 + wn + j * 16 + lr;
        #pragma unroll
        for (int r = 0; r < 4; r++)
          Out[(size_t)(m + r) * DIM + n] = acc[i][j][r] + bj[j];
      }
    }
  } else if (mode == 2) {
    // Vw f16 [b,h,d,s]: within each 64-kk group, pos = pair*32+quadk*8+(nt&1)*4+j,
    // then 16B-chunk XOR-swizzled by d&7.  (kk = s&63; j==r since s0 is 4-aligned.)
    #pragma unroll
    for (int i = 0; i < 4; i++) {
      int m = m0 + wm + i * 16 + quad * 4;
      int b = m >> 11, s0 = m & 2047;
      int kk0 = s0 & 63;
      int pos = (kk0 >> 5) * 32 + ((kk0 >> 2) & 3) * 8 + ((kk0 >> 4) & 1) * 4;
      int chunk = pos >> 3, off = pos & 7;
      #pragma unroll
      for (int j = 0; j < 4; j++) {
        int n = n0 + wn + j * 16 + lr;
        int h = n >> 6, d = n & 63;
        uint2 pk;
        pk.x = pack_f16(acc[i][j][0] + bj[j], acc[i][j][1] + bj[j]);
        pk.y = pack_f16(acc[i][j][2] + bj[j], acc[i][j][3] + bj[j]);
        int idx = (s0 & ~63) + ((chunk ^ (d & 7)) << 3) + off;
        *(uint2*)&Vw[((size_t)(b * NH + h) * HD + d) * SEQ + idx] = pk;
      }
    }
  } else {
    uint16_t* Dst = (mode == 0) ? Qw : Kw;
    float scale = (mode == 0) ? 0.18033688f : 1.0f;   // HD^-0.5 * log2(e) folded into Q
    #pragma unroll
    for (int i = 0; i < 4; i++) {
      int m = m0 + wm + i * 16 + quad * 4;
      int b = m >> 11, s0 = m & 2047;
      #pragma unroll
      for (int j = 0; j < 4; j++) {
        int n = n0 + wn + j * 16 + lr;
        int h = n >> 6, d = n & 63;
        #pragma unroll
        for (int r = 0; r < 4; r++) {
          float v = (acc[i][j][r] + bj[j]) * scale;
          int s = s0 + r;
          int dd = (mode == 1) ? ((((d >> 3) ^ (s & 7)) << 3) + (d & 7)) : d;
          Dst[((size_t)(b * NH + h) * SEQ + s) * HD + dd] = f2bf(v);
        }
      }
    }
  }
}

// ---------------- flash attention: 4 waves x 32 q/wave, 128-q block, 2-phase ----
// Round-10 body (81 µs): q-group-shared K/V frags, T5 setprio on MFMA clusters.
__global__ __launch_bounds__(256, 3) void flash_kernel(
    const uint16_t* __restrict__ Qg, const uint16_t* __restrict__ Kg,
    const uint16_t* __restrict__ Vg, const unsigned long long* __restrict__ Mb,
    uint16_t* __restrict__ AO)
{
  __shared__ alignas(16) uint16_t Ks[2][64 * 64];   // 2 x 8 KB, swizzle baked in Kw
  __shared__ alignas(16) uint16_t Vs[2][64 * 64];   // 2 x 8 KB f16, baked in Vw

  int tid = threadIdx.x, wave = tid >> 6, lane = tid & 63, lr = lane & 15, quad = lane >> 4;

  // XCD swizzle: dispatch id d -> XCD d&7 (round-robin).  768 = 8 * 96.
  int d = blockIdx.x + (blockIdx.y << 4);
  int nid = (d & 7) * 96 + (d >> 3);
  int bh = nid >> 4;
  int q0 = (nid & 15) * 128;
  int b = bh / NH, h = bh - b * NH;

  const uint16_t* Qp = Qg + (size_t)bh * SEQ * HD;
  const uint16_t* Kp = Kg + (size_t)bh * SEQ * HD;
  const uint16_t* Vp = Vg + (size_t)bh * HD * SEQ;
  int qg0 = q0 + wave * 32 + lr;
  int qg1 = qg0 + 16;
  const unsigned long long* Mp0 = Mb + (size_t)b * 32 * SEQ + qg0;
  const unsigned long long* Mp1 = Mp0 + 16;

  int swk = lr & 7, sh0 = quad * 4;

  v8s qf0a = *(const v8s*)&Qp[(size_t)qg0 * HD + quad * 8];
  v8s qf0b = *(const v8s*)&Qp[(size_t)qg0 * HD + 32 + quad * 8];
  v8s qf1a = *(const v8s*)&Qp[(size_t)qg1 * HD + quad * 8];
  v8s qf1b = *(const v8s*)&Qp[(size_t)qg1 * HD + 32 + quad * 8];

  // DMA: 4 waves x 4 calls x 64 lanes x 16B = 16 KB per tile (K 8KB + V 8KB);
  // wave w stages K rows [16w,16w+16) and V rows [16w,16w+16).
  const uint16_t* kgl = Kp + ((size_t)(wave * 16 + (lane >> 3)) * HD + (lane & 7) * 8);
  const uint16_t* vgl = Vp + ((size_t)(wave * 16 + (lane >> 3)) * SEQ + (lane & 7) * 8);
  int lb = wave * 1024;   // uint16 idx: 16 rows x 64 elems per wave

  v8h ones;
  #pragma unroll
  for (int i = 0; i < 8; i++) ones[i] = (_Float16)1.0f;

  v4f acc0[4], acc1[4], lacc0, lacc1;
  v4f vz = {0.f, 0.f, 0.f, 0.f};
  v4f m8 = {-8.f, -8.f, -8.f, -8.f};
  #pragma unroll
  for (int dt = 0; dt < 4; dt++) { acc0[dt] = vz; acc1[dt] = vz; }
  lacc0 = vz; lacc1 = vz;

  // prologue: stage tile 0 into buf 0, fetch its mask words
  gl16(kgl,                   &Ks[0][lb]);
  gl16(kgl + (size_t)8 * HD,  &Ks[0][lb + 512]);
  gl16(vgl,                   &Vs[0][lb]);
  gl16(vgl + (size_t)8 * SEQ, &Vs[0][lb + 512]);
  unsigned long long mw0_cur = Mp0[0];
  unsigned long long mw1_cur = Mp1[0];
  __syncthreads();

  int cur = 0;
  const int NT = SEQ / 64;   // 32
  for (int it = 0; it < NT; ++it) {
    unsigned long long mw0_next = 0, mw1_next = 0;
    if (it + 1 < NT) {
      int kn = (it + 1) * 64;
      gl16(kgl + (size_t)kn * HD,       &Ks[cur ^ 1][lb]);
      gl16(kgl + (size_t)(kn + 8) * HD, &Ks[cur ^ 1][lb + 512]);
      gl16(vgl + kn,                    &Vs[cur ^ 1][lb]);
      gl16(vgl + kn + (size_t)8 * SEQ,  &Vs[cur ^ 1][lb + 512]);
      mw0_next = Mp0[(size_t)(it + 1) * SEQ];
      mw1_next = Mp1[(size_t)(it + 1) * SEQ];
    }

    uint32_t m0lo = (uint32_t)mw0_cur, m0hi = (uint32_t)(mw0_cur >> 32);
    uint32_t m1lo = (uint32_t)mw1_cur, m1hi = (uint32_t)(mw1_cur >> 32);
    v8h pf0[2], pf1[2];
    #pragma unroll
    for (int p = 0; p < 2; p++) {
      v4f sA0 = m8, sB0 = m8, sA1 = m8, sB1 = m8;
      __builtin_amdgcn_s_setprio(1);
      {
        int rowb = ((2 * p) * 16 + lr) << 6;
        v8s kf0 = *(const v8s*)&Ks[cur][rowb + ((quad ^ swk) << 3)];
        v8s kf1 = *(const v8s*)&Ks[cur][rowb + (((quad + 4) ^ swk) << 3)];
        sA0 = __builtin_amdgcn_mfma_f32_16x16x32_bf16(kf0, qf0a, sA0, 0, 0, 0);
        sA0 = __builtin_amdgcn_mfma_f32_16x16x32_bf16(kf1, qf0b, sA0, 0, 0, 0);
        sA1 = __builtin_amdgcn_mfma_f32_16x16x32_bf16(kf0, qf1a, sA1, 0, 0, 0);
        sA1 = __builtin_amdgcn_mfma_f32_16x16x32_bf16(kf1, qf1b, sA1, 0, 0, 0);
      }
      {
        int rowb = ((2 * p + 1) * 16 + lr) << 6;
        v8s kf0 = *(const v8s*)&Ks[cur][rowb + ((quad ^ swk) << 3)];
        v8s kf1 = *(const v8s*)&Ks[cur][rowb + (((quad + 4) ^ swk) << 3)];
        sB0 = __builtin_amdgcn_mfma_f32_16x16x32_bf16(kf0, qf0a, sB0, 0, 0, 0);
        sB0 = __builtin_amdgcn_mfma_f32_16x16x32_bf16(kf1, qf0b, sB0, 0, 0, 0);
        sB1 = __builtin_amdgcn_mfma_f32_16x16x32_bf16(kf0, qf1a, sB1, 0, 0, 0);
        sB1 = __builtin_amdgcn_mfma_f32_16x16x32_bf16(kf1, qf1b, sB1, 0, 0, 0);
      }
      __builtin_amdgcn_s_setprio(0);
      // softmax for both q-groups, this p (4+4 elements each)
      uint32_t w0 = p ? m0hi : m0lo, w1 = p ? m1hi : m1lo;
      uint32_t a0 = (w0 >> sh0) & 15u, b0 = (w0 >> (sh0 + 16)) & 15u;
      uint32_t a1 = (w1 >> sh0) & 15u, b1 = (w1 >> (sh0 + 16)) & 15u;
      float p0[8], p1[8];
      #pragma unroll
      for (int r = 0; r < 4; r++) {
        float e0a = fexp2(sA0[r]), e0b = fexp2(sB0[r]);
        float e1a = fexp2(sA1[r]), e1b = fexp2(sB1[r]);
        p0[r]     = (a0 & (1u << r)) ? e0a : 0.0f;
        p0[4 + r] = (b0 & (1u << r)) ? e0b : 0.0f;
        p1[r]     = (a1 & (1u << r)) ? e1a : 0.0f;
        p1[4 + r] = (b1 & (1u << r)) ? e1b : 0.0f;
      }
      union { uint4 u; v8h h; } c0, c1;
      c0.u.x = pack_f16(p0[0], p0[1]); c0.u.y = pack_f16(p0[2], p0[3]);
      c0.u.z = pack_f16(p0[4], p0[5]); c0.u.w = pack_f16(p0[6], p0[7]);
      c1.u.x = pack_f16(p1[0], p1[1]); c1.u.y = pack_f16(p1[2], p1[3]);
      c1.u.z = pack_f16(p1[4], p1[5]); c1.u.w = pack_f16(p1[6], p1[7]);
      pf0[p] = c0.h;
      pf1[p] = c1.h;
    }

    // O^T += V^T.P^T : one b128 A-frag per (dt, pair), shared across q-groups
    __builtin_amdgcn_s_setprio(1);
    #pragma unroll
    for (int dt = 0; dt < 4; dt++) {
      int rowb = (dt * 16 + lr) << 6;
      #pragma unroll
      for (int p = 0; p < 2; p++) {
        v8h vv = *(const v8h*)&Vs[cur][rowb + (((p * 4 + quad) ^ swk) << 3)];
        acc0[dt] = __builtin_amdgcn_mfma_f32_16x16x32_f16(vv, pf0[p], acc0[dt], 0, 0, 0);
        acc1[dt] = __builtin_amdgcn_mfma_f32_16x16x32_f16(vv, pf1[p], acc1[dt], 0, 0, 0);
      }
    }
    // row-sum of P via ones-A MFMA: every lane gets full sum (all rows equal)
    lacc0 = __builtin_amdgcn_mfma_f32_16x16x32_f16(ones, pf0[0], lacc0, 0, 0, 0);
    lacc0 = __builtin_amdgcn_mfma_f32_16x16x32_f16(ones, pf0[1], lacc0, 0, 0, 0);
    lacc1 = __builtin_amdgcn_mfma_f32_16x16x32_f16(ones, pf1[0], lacc1, 0, 0, 0);
    lacc1 = __builtin_amdgcn_mfma_f32_16x16x32_f16(ones, pf1[1], lacc1, 0, 0, 0);
    __builtin_amdgcn_s_setprio(0);

    __syncthreads();     // drains this wave's DMA (vmcnt) late, then barrier
    mw0_cur = mw0_next;
    mw1_cur = mw1_next;
    cur ^= 1;
  }

  float ri0 = 1.0f / lacc0[0];
  float ri1 = 1.0f / lacc1[0];

  #pragma unroll
  for (int dt = 0; dt < 4; dt++) {
    uint2 pk;
    pk.x = pack_bf16(acc0[dt][0] * ri0, acc0[dt][1] * ri0);
    pk.y = pack_bf16(acc0[dt][2] * ri0, acc0[dt][3] * ri0);
    *(uint2*)&AO[(size_t)(b * SEQ + qg0) * DIM + h * HD + dt * 16 + sh0] = pk;
    pk.x = pack_bf16(acc1[dt][0] * ri1, acc1[dt][1] * ri1);
    pk.y = pack_bf16(acc1[dt][2] * ri1, acc1[dt][3] * ri1);
    *(uint2*)&AO[(size_t)(b * SEQ + qg1) * DIM + h * HD + dt * 16 + sh0] = pk;
  }
}

// ---------------- launch ----------------
extern "C" void kernel_launch(void* const* d_in, const int* in_sizes, int n_in,
                              void* d_out, int out_size, void* d_ws, size_t ws_size,
                              hipStream_t stream) {
  const float* from_t = (const float*)d_in[0];
  const float* to_t   = (const float*)d_in[1];
  const int*   maski  = (const int*)d_in[2];
  const float* Wq = (const float*)d_in[3];  const float* bq = (const float*)d_in[4];
  const float* Wk = (const float*)d_in[5];  const float* bk = (const float*)d_in[6];
  const float* Wv = (const float*)d_in[7];  const float* bv = (const float*)d_in[8];
  const float* Wo = (const float*)d_in[9];  const float* bo = (const float*)d_in[10];

  char* ws = (char*)d_ws;
  size_t off = 0;
  uint16_t* Xf = (uint16_t*)(ws + off); off += (size_t)MROWS * DIM * 2;
  uint16_t* Xt = (uint16_t*)(ws + off); off += (size_t)MROWS * DIM * 2;
  uint16_t* WT = (uint16_t*)(ws + off); off += (size_t)4 * DIM * DIM * 2;
  unsigned long long* Mbits = (unsigned long long*)(ws + off);
  off += (size_t)BSZ * 32 * SEQ * 8;                                    // 2 MB
  uint16_t* Qw = (uint16_t*)(ws + off); off += (size_t)MROWS * DIM * 2; // [b,h,s,d] bf16
  uint16_t* Kw = (uint16_t*)(ws + off); off += (size_t)MROWS * DIM * 2; // [b,h,s,d] bf16 swz
  uint16_t* Vw = (uint16_t*)(ws + off); off += (size_t)MROWS * DIM * 2; // [b,h,d,s] f16 perm+swz
  uint16_t* AO = (uint16_t*)(ws + off); off += (size_t)MROWS * DIM * 2; // [m,768] bf16
  float* Out = (float*)d_out;

  prepass_kernel<<<CVT_BLKS + WT_BLKS + MASK_BLKS, 256, 0, stream>>>(
      from_t, to_t, Xf, Xt, Wq, Wk, Wv, Wo, WT, maski, Mbits);

  gemm_kernel<<<dim3(64, 6, 3), 256, 0, stream>>>(Xf, Xt, WT, AO, bq, bk, bv, bo,
                                                  Qw, Kw, Vw, Out, 0);
  flash_kernel<<<dim3(SEQ / 128, BSZ * NH), 256, 0, stream>>>(Qw, Kw, Vw, Mbits, AO);
  gemm_kernel<<<dim3(64, 6, 1), 256, 0, stream>>>(Xf, Xt, WT, AO, bq, bk, bv, bo,
                                                  Qw, Kw, Vw, Out, 3);
}

// Round 13
// 304.555 us; speedup vs baseline: 1.0635x; 1.0023x over previous
//
#include <hip/hip_runtime.h>
#include <stdint.h>

#define DIM 768
#define NH 12
#define HD 64
#define BSZ 4
#define SEQ 2048
#define MROWS (BSZ*SEQ)   // 8192

typedef __attribute__((ext_vector_type(8))) short v8s;        // 8 bf16 (4 VGPRs)
typedef __attribute__((ext_vector_type(4))) float v4f;        // 4 fp32 acc
typedef __attribute__((ext_vector_type(8))) _Float16 v8h;     // 8 f16 (4 VGPRs)
typedef __attribute__((ext_vector_type(2))) __fp16 v2fp;      // cvt_pkrtz native type

__device__ __forceinline__ uint16_t f2bf(float x) {
  union { float f; uint32_t u; } v; v.f = x;
  uint32_t r = v.u + 0x7fffu + ((v.u >> 16) & 1u);   // RNE
  return (uint16_t)(r >> 16);
}

#if __has_builtin(__builtin_amdgcn_cvt_pk_bf16_f32)
typedef __attribute__((ext_vector_type(2))) __bf16 v2bf;
__device__ __forceinline__ uint32_t pack_bf16(float a, float b) {
  union { v2bf v; uint32_t u; } c;
  c.v = __builtin_amdgcn_cvt_pk_bf16_f32(a, b);
  return c.u;
}
#else
__device__ __forceinline__ uint32_t pack_bf16(float a, float b) {
  return (uint32_t)f2bf(a) | ((uint32_t)f2bf(b) << 16);
}
#endif

__device__ __forceinline__ uint32_t pack_f16(float a, float b) {
#if __has_builtin(__builtin_amdgcn_cvt_pkrtz)
  union { v2fp h; uint32_t u; } c;
  c.h = __builtin_amdgcn_cvt_pkrtz(a, b);
  return c.u;
#else
  union { _Float16 h[2]; uint32_t u; } c;
  c.h[0] = (_Float16)a; c.h[1] = (_Float16)b; return c.u;
#endif
}

__device__ __forceinline__ float fexp2(float x) {
#if __has_builtin(__builtin_amdgcn_exp2f)
  return __builtin_amdgcn_exp2f(x);
#else
  return exp2f(x);
#endif
}

// bit-spread: 16-bit c -> 64-bit with bit i of c at position 4i
__device__ __forceinline__ unsigned long long spread4(uint32_t c) {
  unsigned long long x = c & 0xFFFFu;
  x = (x | (x << 24)) & 0x000000FF000000FFull;
  x = (x | (x << 12)) & 0x000F000F000F000Full;
  x = (x | (x << 6))  & 0x0303030303030303ull;
  x = (x | (x << 3))  & 0x1111111111111111ull;
  return x;
}

// async global->LDS, 16B per lane; LDS dst = wave-uniform base + lane*16
__device__ __forceinline__ void gl16(const void* g, void* l) {
  __builtin_amdgcn_global_load_lds(
      (const __attribute__((address_space(1))) unsigned int*)g,
      (__attribute__((address_space(3))) unsigned int*)l, 16, 0, 0);
}

// vmcnt(0)-drain + raw barrier pair, placed AFTER compute (2-phase pipeline)
__device__ __forceinline__ void pipe_sync() {
  asm volatile("s_waitcnt vmcnt(0)" ::: "memory");
  __builtin_amdgcn_s_barrier();
  __builtin_amdgcn_sched_barrier(0);   // keep next tile's ds_reads below barrier
}

// ------- fused pre-pass: cvt_bf16 + wtrans + mask_bits (ONE launch) ------------
// Mask section int4-vectorized (16B/lane, 1 KB/wave): four ballots + 16->64
// bit-spread assemble each 16-lane group's u64 word (R12: -14.5 µs vs scalar).
#define CVT_BLKS  12288   // 2 * MROWS*DIM/4 / 256
#define WT_BLKS   2304    // 4 * 24 * 24
#define MASK_BLKS 16384   // 65536 groups (4 kt-words each) / 4 waves-per-block
__global__ __launch_bounds__(256) void prepass_kernel(
    const float* __restrict__ from_t, const float* __restrict__ to_t,
    uint16_t* __restrict__ Xf, uint16_t* __restrict__ Xt,
    const float* __restrict__ Wq, const float* __restrict__ Wk,
    const float* __restrict__ Wv, const float* __restrict__ Wo,
    uint16_t* __restrict__ WT,
    const int* __restrict__ maski, unsigned long long* __restrict__ Mbits)
{
  __shared__ float tile[32][33];
  int blk = blockIdx.x, tid = threadIdx.x;
  if (blk < CVT_BLKS) {
    // fp32 -> bf16, both X tensors
    int n4 = MROWS * DIM / 4;
    int i = blk * 256 + tid;
    const float* src = (i < n4) ? from_t : to_t;
    uint16_t* dst = (i < n4) ? Xf : Xt;
    int j = (i < n4) ? i : i - n4;
    float4 v = ((const float4*)src)[j];
    uint2 o;
    o.x = pack_bf16(v.x, v.y);
    o.y = pack_bf16(v.z, v.w);
    ((uint2*)dst)[j] = o;
  } else if (blk < CVT_BLKS + WT_BLKS) {
    // W [K][N] fp32 -> WT [N][K] bf16
    int r = blk - CVT_BLKS;
    int z = r / 576, rem = r - z * 576;
    int by = rem / 24, bx = rem - by * 24;
    const float* src = (z==0) ? Wq : (z==1) ? Wk : (z==2) ? Wv : Wo;
    uint16_t* dst = WT + (size_t)z * DIM * DIM;
    int tx = tid & 31, ty = tid >> 5;
    int x  = bx * 32 + tx;
    int y0 = by * 32;
    for (int jj = ty; jj < 32; jj += 8)
      tile[jj][tx] = src[(size_t)(y0 + jj) * DIM + x];
    __syncthreads();
    int xo = y0 + tx;
    for (int jj = ty; jj < 32; jj += 8)
      dst[(size_t)(bx * 32 + jj) * DIM + xo] = f2bf(tile[tx][jj]);
  } else {
    // mask int32 -> u64 bitmask [b][kt][q], 1 KB contiguous per wave.
    int gtid = (blk - CVT_BLKS - WT_BLKS) * 256 + tid;
    int g = gtid >> 6;
    int lane = tid & 63;
    int b   = g >> 14;
    int q   = (g >> 3) & 2047;
    int ktb = (g & 7) * 4;
    size_t base = ((size_t)b * SEQ + q) * SEQ + (size_t)ktb * 64;
    int4 m = *(const int4*)&maski[base + (lane >> 4) * 64 + (lane & 15) * 4];
    unsigned long long b0 = __ballot(m.x != 0);
    unsigned long long b1 = __ballot(m.y != 0);
    unsigned long long b2 = __ballot(m.z != 0);
    unsigned long long b3 = __ballot(m.w != 0);
    int qd = lane >> 4, sh = qd * 16;
    unsigned long long word =  spread4((uint32_t)(b0 >> sh))
                            | (spread4((uint32_t)(b1 >> sh)) << 1)
                            | (spread4((uint32_t)(b2 >> sh)) << 2)
                            | (spread4((uint32_t)(b3 >> sh)) << 3);
    if ((lane & 15) == 0)
      Mbits[((size_t)b * 32 + ktb + qd) * SEQ + q] = word;
  }
}

// ---------------- GEMM (2-phase pipelined DMA staging): C = A(bf16)@WT^T + bias -
// Round-7 body; now used for modes 0-2 (QKV) only.  Mode 3 moved to
// gemm64_kernel (the 128x128 grid gave only 384 blocks = 1.5 blocks/CU).
// mode 0: Q -> Qw [b,h,s,d]*(SCALE*log2e)  mode 1: K -> Kw (d-chunk swz by s&7)
// mode 2: V -> Vw [b,h,d,s] f16, kk pair-permuted + chunk swz by d&7
__global__ __launch_bounds__(256) void gemm_kernel(
    const uint16_t* __restrict__ Xf, const uint16_t* __restrict__ Xt,
    const uint16_t* __restrict__ WT,
    const float* __restrict__ bq, const float* __restrict__ bk,
    const float* __restrict__ bv,
    uint16_t* __restrict__ Qw, uint16_t* __restrict__ Kw, uint16_t* __restrict__ Vw)
{
  __shared__ alignas(16) uint16_t As[2][128 * 32];
  __shared__ alignas(16) uint16_t Bs[2][128 * 32];
  int mode = blockIdx.z;
  const uint16_t* A = (mode == 0) ? Xf : Xt;
  const uint16_t* W = WT + (size_t)mode * DIM * DIM;
  const float* bias = (mode == 0) ? bq : (mode == 1) ? bk : bv;

  int m0 = blockIdx.x * 128, n0 = blockIdx.y * 128;
  int tid = threadIdx.x;
  int wave = tid >> 6, lane = tid & 63, lr = lane & 15, quad = lane >> 4;
  int wm = (wave >> 1) * 64, wn = (wave & 1) * 64;

  int seg = (lane & 3) ^ ((lane >> 3) & 3);
  const uint16_t* agl = A + (size_t)(m0 + wave * 32 + (lane >> 2)) * DIM + seg * 8;
  const uint16_t* bgl = W + (size_t)(n0 + wave * 32 + (lane >> 2)) * DIM + seg * 8;
  int lb = wave * 1024;             // uint16 idx; second call adds 512
  int ck = (lr >> 1) & 3;

  v4f acc[4][4];
  v4f vz = {0.f, 0.f, 0.f, 0.f};
  #pragma unroll
  for (int i = 0; i < 4; i++)
    #pragma unroll
    for (int j = 0; j < 4; j++) acc[i][j] = vz;

  // prologue: stage k0=0 into buf 0
  gl16(agl,            &As[0][lb]);
  gl16(agl + 16 * DIM, &As[0][lb + 512]);
  gl16(bgl,            &Bs[0][lb]);
  gl16(bgl + 16 * DIM, &Bs[0][lb + 512]);
  pipe_sync();

  int cur = 0;
  const int NT = DIM / 32;   // 24
  for (int t = 0; t < NT; ++t) {
    if (t + 1 < NT) {
      int kn = (t + 1) * 32;
      gl16(agl + kn,            &As[cur ^ 1][lb]);
      gl16(agl + kn + 16 * DIM, &As[cur ^ 1][lb + 512]);
      gl16(bgl + kn,            &Bs[cur ^ 1][lb]);
      gl16(bgl + kn + 16 * DIM, &Bs[cur ^ 1][lb + 512]);
    }
    v8s af[4], bfr[4];
    #pragma unroll
    for (int i = 0; i < 4; i++)
      af[i] = *(const v8s*)&As[cur][(wm + i * 16 + lr) * 32 + ((quad ^ ck) << 3)];
    #pragma unroll
    for (int j = 0; j < 4; j++)
      bfr[j] = *(const v8s*)&Bs[cur][(wn + j * 16 + lr) * 32 + ((quad ^ ck) << 3)];
    #pragma unroll
    for (int i = 0; i < 4; i++)
      #pragma unroll
      for (int j = 0; j < 4; j++)
        acc[i][j] = __builtin_amdgcn_mfma_f32_16x16x32_bf16(af[i], bfr[j], acc[i][j], 0, 0, 0);
    if (t + 1 < NT) pipe_sync();
    cur ^= 1;
  }

  float bj[4];
  #pragma unroll
  for (int j = 0; j < 4; j++) bj[j] = bias[n0 + wn + j * 16 + lr];

  if (mode == 2) {
    // Vw f16 [b,h,d,s]: within each 64-kk group, pos = pair*32+quadk*8+(nt&1)*4+j,
    // then 16B-chunk XOR-swizzled by d&7.  (kk = s&63; j==r since s0 is 4-aligned.)
    #pragma unroll
    for (int i = 0; i < 4; i++) {
      int m = m0 + wm + i * 16 + quad * 4;
      int b = m >> 11, s0 = m & 2047;
      int kk0 = s0 & 63;
      int pos = (kk0 >> 5) * 32 + ((kk0 >> 2) & 3) * 8 + ((kk0 >> 4) & 1) * 4;
      int chunk = pos >> 3, off = pos & 7;
      #pragma unroll
      for (int j = 0; j < 4; j++) {
        int n = n0 + wn + j * 16 + lr;
        int h = n >> 6, d = n & 63;
        uint2 pk;
        pk.x = pack_f16(acc[i][j][0] + bj[j], acc[i][j][1] + bj[j]);
        pk.y = pack_f16(acc[i][j][2] + bj[j], acc[i][j][3] + bj[j]);
        int idx = (s0 & ~63) + ((chunk ^ (d & 7)) << 3) + off;
        *(uint2*)&Vw[((size_t)(b * NH + h) * HD + d) * SEQ + idx] = pk;
      }
    }
  } else {
    uint16_t* Dst = (mode == 0) ? Qw : Kw;
    float scale = (mode == 0) ? 0.18033688f : 1.0f;   // HD^-0.5 * log2(e) folded into Q
    #pragma unroll
    for (int i = 0; i < 4; i++) {
      int m = m0 + wm + i * 16 + quad * 4;
      int b = m >> 11, s0 = m & 2047;
      #pragma unroll
      for (int j = 0; j < 4; j++) {
        int n = n0 + wn + j * 16 + lr;
        int h = n >> 6, d = n & 63;
        #pragma unroll
        for (int r = 0; r < 4; r++) {
          float v = (acc[i][j][r] + bj[j]) * scale;
          int s = s0 + r;
          int dd = (mode == 1) ? ((((d >> 3) ^ (s & 7)) << 3) + (d & 7)) : d;
          Dst[((size_t)(b * NH + h) * SEQ + s) * HD + dd] = f2bf(v);
        }
      }
    }
  }
}

// ---------------- O-projection GEMM: BM=64 x BN=128 tile --------------------
// Same 2-phase dbuf + source-side XOR swizzle as gemm_kernel, but 64-row M-tile:
// grid (8192/64)x(768/128) = 768 blocks = 3 blocks/CU = 12 waves/CU (the
// 128x128 version gave only 384 blocks = 6 waves/CU — latency-exposed).
// Waves 2x2: wave handles 32x64 (acc[2][4]).  A: 1 gl16/wave (16 rows);
// B: 2 gl16/wave (32 rows).  LDS 24 KB.
__global__ __launch_bounds__(256) void gemm64_kernel(
    const uint16_t* __restrict__ AO, const uint16_t* __restrict__ WT,
    const float* __restrict__ bo, float* __restrict__ Out)
{
  __shared__ alignas(16) uint16_t As[2][64 * 32];
  __shared__ alignas(16) uint16_t Bs[2][128 * 32];
  const uint16_t* W = WT + (size_t)3 * DIM * DIM;

  int m0 = blockIdx.x * 64, n0 = blockIdx.y * 128;
  int tid = threadIdx.x;
  int wave = tid >> 6, lane = tid & 63, lr = lane & 15, quad = lane >> 4;
  int wm = (wave >> 1) * 32, wn = (wave & 1) * 64;

  int seg = (lane & 3) ^ ((lane >> 3) & 3);
  const uint16_t* agl = AO + (size_t)(m0 + wave * 16 + (lane >> 2)) * DIM + seg * 8;
  const uint16_t* bgl = W  + (size_t)(n0 + wave * 32 + (lane >> 2)) * DIM + seg * 8;
  int lba = wave * 512;    // uint16 idx: 16 rows x 32 elems per wave
  int lbb = wave * 1024;   // uint16 idx: 32 rows; second call adds 512
  int ck = (lr >> 1) & 3;

  v4f acc[2][4];
  v4f vz = {0.f, 0.f, 0.f, 0.f};
  #pragma unroll
  for (int i = 0; i < 2; i++)
    #pragma unroll
    for (int j = 0; j < 4; j++) acc[i][j] = vz;

  // prologue: stage k0=0 into buf 0
  gl16(agl,            &As[0][lba]);
  gl16(bgl,            &Bs[0][lbb]);
  gl16(bgl + 16 * DIM, &Bs[0][lbb + 512]);
  pipe_sync();

  int cur = 0;
  const int NT = DIM / 32;   // 24
  for (int t = 0; t < NT; ++t) {
    if (t + 1 < NT) {
      int kn = (t + 1) * 32;
      gl16(agl + kn,            &As[cur ^ 1][lba]);
      gl16(bgl + kn,            &Bs[cur ^ 1][lbb]);
      gl16(bgl + kn + 16 * DIM, &Bs[cur ^ 1][lbb + 512]);
    }
    v8s af[2], bfr[4];
    #pragma unroll
    for (int i = 0; i < 2; i++)
      af[i] = *(const v8s*)&As[cur][(wm + i * 16 + lr) * 32 + ((quad ^ ck) << 3)];
    #pragma unroll
    for (int j = 0; j < 4; j++)
      bfr[j] = *(const v8s*)&Bs[cur][(wn + j * 16 + lr) * 32 + ((quad ^ ck) << 3)];
    #pragma unroll
    for (int i = 0; i < 2; i++)
      #pragma unroll
      for (int j = 0; j < 4; j++)
        acc[i][j] = __builtin_amdgcn_mfma_f32_16x16x32_bf16(af[i], bfr[j], acc[i][j], 0, 0, 0);
    if (t + 1 < NT) pipe_sync();
    cur ^= 1;
  }

  float bj[4];
  #pragma unroll
  for (int j = 0; j < 4; j++) bj[j] = bo[n0 + wn + j * 16 + lr];

  #pragma unroll
  for (int i = 0; i < 2; i++) {
    int m = m0 + wm + i * 16 + quad * 4;
    #pragma unroll
    for (int j = 0; j < 4; j++) {
      int n = n0 + wn + j * 16 + lr;
      #pragma unroll
      for (int r = 0; r < 4; r++)
        Out[(size_t)(m + r) * DIM + n] = acc[i][j][r] + bj[j];
    }
  }
}

// ---------------- flash attention: 4 waves x 32 q/wave, 128-q block, 2-phase ----
// Round-10 body (81 µs): q-group-shared K/V frags, T5 setprio on MFMA clusters.
__global__ __launch_bounds__(256, 3) void flash_kernel(
    const uint16_t* __restrict__ Qg, const uint16_t* __restrict__ Kg,
    const uint16_t* __restrict__ Vg, const unsigned long long* __restrict__ Mb,
    uint16_t* __restrict__ AO)
{
  __shared__ alignas(16) uint16_t Ks[2][64 * 64];   // 2 x 8 KB, swizzle baked in Kw
  __shared__ alignas(16) uint16_t Vs[2][64 * 64];   // 2 x 8 KB f16, baked in Vw

  int tid = threadIdx.x, wave = tid >> 6, lane = tid & 63, lr = lane & 15, quad = lane >> 4;

  // XCD swizzle: dispatch id d -> XCD d&7 (round-robin).  768 = 8 * 96.
  int d = blockIdx.x + (blockIdx.y << 4);
  int nid = (d & 7) * 96 + (d >> 3);
  int bh = nid >> 4;
  int q0 = (nid & 15) * 128;
  int b = bh / NH, h = bh - b * NH;

  const uint16_t* Qp = Qg + (size_t)bh * SEQ * HD;
  const uint16_t* Kp = Kg + (size_t)bh * SEQ * HD;
  const uint16_t* Vp = Vg + (size_t)bh * HD * SEQ;
  int qg0 = q0 + wave * 32 + lr;
  int qg1 = qg0 + 16;
  const unsigned long long* Mp0 = Mb + (size_t)b * 32 * SEQ + qg0;
  const unsigned long long* Mp1 = Mp0 + 16;

  int swk = lr & 7, sh0 = quad * 4;

  v8s qf0a = *(const v8s*)&Qp[(size_t)qg0 * HD + quad * 8];
  v8s qf0b = *(const v8s*)&Qp[(size_t)qg0 * HD + 32 + quad * 8];
  v8s qf1a = *(const v8s*)&Qp[(size_t)qg1 * HD + quad * 8];
  v8s qf1b = *(const v8s*)&Qp[(size_t)qg1 * HD + 32 + quad * 8];

  // DMA: 4 waves x 4 calls x 64 lanes x 16B = 16 KB per tile (K 8KB + V 8KB);
  // wave w stages K rows [16w,16w+16) and V rows [16w,16w+16).
  const uint16_t* kgl = Kp + ((size_t)(wave * 16 + (lane >> 3)) * HD + (lane & 7) * 8);
  const uint16_t* vgl = Vp + ((size_t)(wave * 16 + (lane >> 3)) * SEQ + (lane & 7) * 8);
  int lb = wave * 1024;   // uint16 idx: 16 rows x 64 elems per wave

  v8h ones;
  #pragma unroll
  for (int i = 0; i < 8; i++) ones[i] = (_Float16)1.0f;

  v4f acc0[4], acc1[4], lacc0, lacc1;
  v4f vz = {0.f, 0.f, 0.f, 0.f};
  v4f m8 = {-8.f, -8.f, -8.f, -8.f};
  #pragma unroll
  for (int dt = 0; dt < 4; dt++) { acc0[dt] = vz; acc1[dt] = vz; }
  lacc0 = vz; lacc1 = vz;

  // prologue: stage tile 0 into buf 0, fetch its mask words
  gl16(kgl,                   &Ks[0][lb]);
  gl16(kgl + (size_t)8 * HD,  &Ks[0][lb + 512]);
  gl16(vgl,                   &Vs[0][lb]);
  gl16(vgl + (size_t)8 * SEQ, &Vs[0][lb + 512]);
  unsigned long long mw0_cur = Mp0[0];
  unsigned long long mw1_cur = Mp1[0];
  __syncthreads();

  int cur = 0;
  const int NT = SEQ / 64;   // 32
  for (int it = 0; it < NT; ++it) {
    unsigned long long mw0_next = 0, mw1_next = 0;
    if (it + 1 < NT) {
      int kn = (it + 1) * 64;
      gl16(kgl + (size_t)kn * HD,       &Ks[cur ^ 1][lb]);
      gl16(kgl + (size_t)(kn + 8) * HD, &Ks[cur ^ 1][lb + 512]);
      gl16(vgl + kn,                    &Vs[cur ^ 1][lb]);
      gl16(vgl + kn + (size_t)8 * SEQ,  &Vs[cur ^ 1][lb + 512]);
      mw0_next = Mp0[(size_t)(it + 1) * SEQ];
      mw1_next = Mp1[(size_t)(it + 1) * SEQ];
    }

    uint32_t m0lo = (uint32_t)mw0_cur, m0hi = (uint32_t)(mw0_cur >> 32);
    uint32_t m1lo = (uint32_t)mw1_cur, m1hi = (uint32_t)(mw1_cur >> 32);
    v8h pf0[2], pf1[2];
    #pragma unroll
    for (int p = 0; p < 2; p++) {
      v4f sA0 = m8, sB0 = m8, sA1 = m8, sB1 = m8;
      __builtin_amdgcn_s_setprio(1);
      {
        int rowb = ((2 * p) * 16 + lr) << 6;
        v8s kf0 = *(const v8s*)&Ks[cur][rowb + ((quad ^ swk) << 3)];
        v8s kf1 = *(const v8s*)&Ks[cur][rowb + (((quad + 4) ^ swk) << 3)];
        sA0 = __builtin_amdgcn_mfma_f32_16x16x32_bf16(kf0, qf0a, sA0, 0, 0, 0);
        sA0 = __builtin_amdgcn_mfma_f32_16x16x32_bf16(kf1, qf0b, sA0, 0, 0, 0);
        sA1 = __builtin_amdgcn_mfma_f32_16x16x32_bf16(kf0, qf1a, sA1, 0, 0, 0);
        sA1 = __builtin_amdgcn_mfma_f32_16x16x32_bf16(kf1, qf1b, sA1, 0, 0, 0);
      }
      {
        int rowb = ((2 * p + 1) * 16 + lr) << 6;
        v8s kf0 = *(const v8s*)&Ks[cur][rowb + ((quad ^ swk) << 3)];
        v8s kf1 = *(const v8s*)&Ks[cur][rowb + (((quad + 4) ^ swk) << 3)];
        sB0 = __builtin_amdgcn_mfma_f32_16x16x32_bf16(kf0, qf0a, sB0, 0, 0, 0);
        sB0 = __builtin_amdgcn_mfma_f32_16x16x32_bf16(kf1, qf0b, sB0, 0, 0, 0);
        sB1 = __builtin_amdgcn_mfma_f32_16x16x32_bf16(kf0, qf1a, sB1, 0, 0, 0);
        sB1 = __builtin_amdgcn_mfma_f32_16x16x32_bf16(kf1, qf1b, sB1, 0, 0, 0);
      }
      __builtin_amdgcn_s_setprio(0);
      // softmax for both q-groups, this p (4+4 elements each)
      uint32_t w0 = p ? m0hi : m0lo, w1 = p ? m1hi : m1lo;
      uint32_t a0 = (w0 >> sh0) & 15u, b0 = (w0 >> (sh0 + 16)) & 15u;
      uint32_t a1 = (w1 >> sh0) & 15u, b1 = (w1 >> (sh0 + 16)) & 15u;
      float p0[8], p1[8];
      #pragma unroll
      for (int r = 0; r < 4; r++) {
        float e0a = fexp2(sA0[r]), e0b = fexp2(sB0[r]);
        float e1a = fexp2(sA1[r]), e1b = fexp2(sB1[r]);
        p0[r]     = (a0 & (1u << r)) ? e0a : 0.0f;
        p0[4 + r] = (b0 & (1u << r)) ? e0b : 0.0f;
        p1[r]     = (a1 & (1u << r)) ? e1a : 0.0f;
        p1[4 + r] = (b1 & (1u << r)) ? e1b : 0.0f;
      }
      union { uint4 u; v8h h; } c0, c1;
      c0.u.x = pack_f16(p0[0], p0[1]); c0.u.y = pack_f16(p0[2], p0[3]);
      c0.u.z = pack_f16(p0[4], p0[5]); c0.u.w = pack_f16(p0[6], p0[7]);
      c1.u.x = pack_f16(p1[0], p1[1]); c1.u.y = pack_f16(p1[2], p1[3]);
      c1.u.z = pack_f16(p1[4], p1[5]); c1.u.w = pack_f16(p1[6], p1[7]);
      pf0[p] = c0.h;
      pf1[p] = c1.h;
    }

    // O^T += V^T.P^T : one b128 A-frag per (dt, pair), shared across q-groups
    __builtin_amdgcn_s_setprio(1);
    #pragma unroll
    for (int dt = 0; dt < 4; dt++) {
      int rowb = (dt * 16 + lr) << 6;
      #pragma unroll
      for (int p = 0; p < 2; p++) {
        v8h vv = *(const v8h*)&Vs[cur][rowb + (((p * 4 + quad) ^ swk) << 3)];
        acc0[dt] = __builtin_amdgcn_mfma_f32_16x16x32_f16(vv, pf0[p], acc0[dt], 0, 0, 0);
        acc1[dt] = __builtin_amdgcn_mfma_f32_16x16x32_f16(vv, pf1[p], acc1[dt], 0, 0, 0);
      }
    }
    // row-sum of P via ones-A MFMA: every lane gets full sum (all rows equal)
    lacc0 = __builtin_amdgcn_mfma_f32_16x16x32_f16(ones, pf0[0], lacc0, 0, 0, 0);
    lacc0 = __builtin_amdgcn_mfma_f32_16x16x32_f16(ones, pf0[1], lacc0, 0, 0, 0);
    lacc1 = __builtin_amdgcn_mfma_f32_16x16x32_f16(ones, pf1[0], lacc1, 0, 0, 0);
    lacc1 = __builtin_amdgcn_mfma_f32_16x16x32_f16(ones, pf1[1], lacc1, 0, 0, 0);
    __builtin_amdgcn_s_setprio(0);

    __syncthreads();     // drains this wave's DMA (vmcnt) late, then barrier
    mw0_cur = mw0_next;
    mw1_cur = mw1_next;
    cur ^= 1;
  }

  float ri0 = 1.0f / lacc0[0];
  float ri1 = 1.0f / lacc1[0];

  #pragma unroll
  for (int dt = 0; dt < 4; dt++) {
    uint2 pk;
    pk.x = pack_bf16(acc0[dt][0] * ri0, acc0[dt][1] * ri0);
    pk.y = pack_bf16(acc0[dt][2] * ri0, acc0[dt][3] * ri0);
    *(uint2*)&AO[(size_t)(b * SEQ + qg0) * DIM + h * HD + dt * 16 + sh0] = pk;
    pk.x = pack_bf16(acc1[dt][0] * ri1, acc1[dt][1] * ri1);
    pk.y = pack_bf16(acc1[dt][2] * ri1, acc1[dt][3] * ri1);
    *(uint2*)&AO[(size_t)(b * SEQ + qg1) * DIM + h * HD + dt * 16 + sh0] = pk;
  }
}

// ---------------- launch ----------------
extern "C" void kernel_launch(void* const* d_in, const int* in_sizes, int n_in,
                              void* d_out, int out_size, void* d_ws, size_t ws_size,
                              hipStream_t stream) {
  const float* from_t = (const float*)d_in[0];
  const float* to_t   = (const float*)d_in[1];
  const int*   maski  = (const int*)d_in[2];
  const float* Wq = (const float*)d_in[3];  const float* bq = (const float*)d_in[4];
  const float* Wk = (const float*)d_in[5];  const float* bk = (const float*)d_in[6];
  const float* Wv = (const float*)d_in[7];  const float* bv = (const float*)d_in[8];
  const float* Wo = (const float*)d_in[9];  const float* bo = (const float*)d_in[10];

  char* ws = (char*)d_ws;
  size_t off = 0;
  uint16_t* Xf = (uint16_t*)(ws + off); off += (size_t)MROWS * DIM * 2;
  uint16_t* Xt = (uint16_t*)(ws + off); off += (size_t)MROWS * DIM * 2;
  uint16_t* WT = (uint16_t*)(ws + off); off += (size_t)4 * DIM * DIM * 2;
  unsigned long long* Mbits = (unsigned long long*)(ws + off);
  off += (size_t)BSZ * 32 * SEQ * 8;                                    // 2 MB
  uint16_t* Qw = (uint16_t*)(ws + off); off += (size_t)MROWS * DIM * 2; // [b,h,s,d] bf16
  uint16_t* Kw = (uint16_t*)(ws + off); off += (size_t)MROWS * DIM * 2; // [b,h,s,d] bf16 swz
  uint16_t* Vw = (uint16_t*)(ws + off); off += (size_t)MROWS * DIM * 2; // [b,h,d,s] f16 perm+swz
  uint16_t* AO = (uint16_t*)(ws + off); off += (size_t)MROWS * DIM * 2; // [m,768] bf16
  float* Out = (float*)d_out;

  prepass_kernel<<<CVT_BLKS + WT_BLKS + MASK_BLKS, 256, 0, stream>>>(
      from_t, to_t, Xf, Xt, Wq, Wk, Wv, Wo, WT, maski, Mbits);

  gemm_kernel<<<dim3(64, 6, 3), 256, 0, stream>>>(Xf, Xt, WT, bq, bk, bv,
                                                  Qw, Kw, Vw);
  flash_kernel<<<dim3(SEQ / 128, BSZ * NH), 256, 0, stream>>>(Qw, Kw, Vw, Mbits, AO);
  gemm64_kernel<<<dim3(128, 6), 256, 0, stream>>>(AO, WT, bo, Out);
}

// Round 14
// 304.191 us; speedup vs baseline: 1.0648x; 1.0012x over previous
//
#include <hip/hip_runtime.h>
#include <stdint.h>

#define DIM 768
#define NH 12
#define HD 64
#define BSZ 4
#define SEQ 2048
#define MROWS (BSZ*SEQ)   // 8192

typedef __attribute__((ext_vector_type(8))) short v8s;        // 8 bf16 (4 VGPRs)
typedef __attribute__((ext_vector_type(4))) float v4f;        // 4 fp32 acc
typedef __attribute__((ext_vector_type(8))) _Float16 v8h;     // 8 f16 (4 VGPRs)
typedef __attribute__((ext_vector_type(2))) __fp16 v2fp;      // cvt_pkrtz native type

__device__ __forceinline__ uint16_t f2bf(float x) {
  union { float f; uint32_t u; } v; v.f = x;
  uint32_t r = v.u + 0x7fffu + ((v.u >> 16) & 1u);   // RNE
  return (uint16_t)(r >> 16);
}

#if __has_builtin(__builtin_amdgcn_cvt_pk_bf16_f32)
typedef __attribute__((ext_vector_type(2))) __bf16 v2bf;
__device__ __forceinline__ uint32_t pack_bf16(float a, float b) {
  union { v2bf v; uint32_t u; } c;
  c.v = __builtin_amdgcn_cvt_pk_bf16_f32(a, b);
  return c.u;
}
#else
__device__ __forceinline__ uint32_t pack_bf16(float a, float b) {
  return (uint32_t)f2bf(a) | ((uint32_t)f2bf(b) << 16);
}
#endif

__device__ __forceinline__ uint32_t pack_f16(float a, float b) {
#if __has_builtin(__builtin_amdgcn_cvt_pkrtz)
  union { v2fp h; uint32_t u; } c;
  c.h = __builtin_amdgcn_cvt_pkrtz(a, b);
  return c.u;
#else
  union { _Float16 h[2]; uint32_t u; } c;
  c.h[0] = (_Float16)a; c.h[1] = (_Float16)b; return c.u;
#endif
}

__device__ __forceinline__ float fexp2(float x) {
#if __has_builtin(__builtin_amdgcn_exp2f)
  return __builtin_amdgcn_exp2f(x);
#else
  return exp2f(x);
#endif
}

// bit-spread: 16-bit c -> 64-bit with bit i of c at position 4i
__device__ __forceinline__ unsigned long long spread4(uint32_t c) {
  unsigned long long x = c & 0xFFFFu;
  x = (x | (x << 24)) & 0x000000FF000000FFull;
  x = (x | (x << 12)) & 0x000F000F000F000Full;
  x = (x | (x << 6))  & 0x0303030303030303ull;
  x = (x | (x << 3))  & 0x1111111111111111ull;
  return x;
}

// async global->LDS, 16B per lane; LDS dst = wave-uniform base + lane*16
__device__ __forceinline__ void gl16(const void* g, void* l) {
  __builtin_amdgcn_global_load_lds(
      (const __attribute__((address_space(1))) unsigned int*)g,
      (__attribute__((address_space(3))) unsigned int*)l, 16, 0, 0);
}

// vmcnt(0)-drain + raw barrier pair, placed AFTER compute (2-phase pipeline)
__device__ __forceinline__ void pipe_sync() {
  asm volatile("s_waitcnt vmcnt(0)" ::: "memory");
  __builtin_amdgcn_s_barrier();
  __builtin_amdgcn_sched_barrier(0);   // keep next tile's ds_reads below barrier
}

// ------- fused pre-pass: cvt_bf16 + wtrans + mask_bits (ONE launch) ------------
// Mask section int4-vectorized (16B/lane, 1 KB/wave): four ballots + 16->64
// bit-spread assemble each 16-lane group's u64 word (R12: -14.5 µs vs scalar).
#define CVT_BLKS  12288   // 2 * MROWS*DIM/4 / 256
#define WT_BLKS   2304    // 4 * 24 * 24
#define MASK_BLKS 16384   // 65536 groups (4 kt-words each) / 4 waves-per-block
__global__ __launch_bounds__(256) void prepass_kernel(
    const float* __restrict__ from_t, const float* __restrict__ to_t,
    uint16_t* __restrict__ Xf, uint16_t* __restrict__ Xt,
    const float* __restrict__ Wq, const float* __restrict__ Wk,
    const float* __restrict__ Wv, const float* __restrict__ Wo,
    uint16_t* __restrict__ WT,
    const int* __restrict__ maski, unsigned long long* __restrict__ Mbits)
{
  __shared__ float tile[32][33];
  int blk = blockIdx.x, tid = threadIdx.x;
  if (blk < CVT_BLKS) {
    // fp32 -> bf16, both X tensors
    int n4 = MROWS * DIM / 4;
    int i = blk * 256 + tid;
    const float* src = (i < n4) ? from_t : to_t;
    uint16_t* dst = (i < n4) ? Xf : Xt;
    int j = (i < n4) ? i : i - n4;
    float4 v = ((const float4*)src)[j];
    uint2 o;
    o.x = pack_bf16(v.x, v.y);
    o.y = pack_bf16(v.z, v.w);
    ((uint2*)dst)[j] = o;
  } else if (blk < CVT_BLKS + WT_BLKS) {
    // W [K][N] fp32 -> WT [N][K] bf16
    int r = blk - CVT_BLKS;
    int z = r / 576, rem = r - z * 576;
    int by = rem / 24, bx = rem - by * 24;
    const float* src = (z==0) ? Wq : (z==1) ? Wk : (z==2) ? Wv : Wo;
    uint16_t* dst = WT + (size_t)z * DIM * DIM;
    int tx = tid & 31, ty = tid >> 5;
    int x  = bx * 32 + tx;
    int y0 = by * 32;
    for (int jj = ty; jj < 32; jj += 8)
      tile[jj][tx] = src[(size_t)(y0 + jj) * DIM + x];
    __syncthreads();
    int xo = y0 + tx;
    for (int jj = ty; jj < 32; jj += 8)
      dst[(size_t)(bx * 32 + jj) * DIM + xo] = f2bf(tile[tx][jj]);
  } else {
    // mask int32 -> u64 bitmask [b][kt][q], 1 KB contiguous per wave.
    int gtid = (blk - CVT_BLKS - WT_BLKS) * 256 + tid;
    int g = gtid >> 6;
    int lane = tid & 63;
    int b   = g >> 14;
    int q   = (g >> 3) & 2047;
    int ktb = (g & 7) * 4;
    size_t base = ((size_t)b * SEQ + q) * SEQ + (size_t)ktb * 64;
    int4 m = *(const int4*)&maski[base + (lane >> 4) * 64 + (lane & 15) * 4];
    unsigned long long b0 = __ballot(m.x != 0);
    unsigned long long b1 = __ballot(m.y != 0);
    unsigned long long b2 = __ballot(m.z != 0);
    unsigned long long b3 = __ballot(m.w != 0);
    int qd = lane >> 4, sh = qd * 16;
    unsigned long long word =  spread4((uint32_t)(b0 >> sh))
                            | (spread4((uint32_t)(b1 >> sh)) << 1)
                            | (spread4((uint32_t)(b2 >> sh)) << 2)
                            | (spread4((uint32_t)(b3 >> sh)) << 3);
    if ((lane & 15) == 0)
      Mbits[((size_t)b * 32 + ktb + qd) * SEQ + q] = word;
  }
}

// ---------------- GEMM (2-phase pipelined DMA staging): QKV ---------------------
// mode 0: Q -> Qw [b,h,s,d]*(SCALE*log2e)  mode 1: K -> Kw (d-chunk swz by s&7)
// mode 2: V -> Vw [b,h,d,s] f16, kk pair-permuted + chunk swz by d&7
__global__ __launch_bounds__(256) void gemm_kernel(
    const uint16_t* __restrict__ Xf, const uint16_t* __restrict__ Xt,
    const uint16_t* __restrict__ WT,
    const float* __restrict__ bq, const float* __restrict__ bk,
    const float* __restrict__ bv,
    uint16_t* __restrict__ Qw, uint16_t* __restrict__ Kw, uint16_t* __restrict__ Vw)
{
  __shared__ alignas(16) uint16_t As[2][128 * 32];
  __shared__ alignas(16) uint16_t Bs[2][128 * 32];
  int mode = blockIdx.z;
  const uint16_t* A = (mode == 0) ? Xf : Xt;
  const uint16_t* W = WT + (size_t)mode * DIM * DIM;
  const float* bias = (mode == 0) ? bq : (mode == 1) ? bk : bv;

  int m0 = blockIdx.x * 128, n0 = blockIdx.y * 128;
  int tid = threadIdx.x;
  int wave = tid >> 6, lane = tid & 63, lr = lane & 15, quad = lane >> 4;
  int wm = (wave >> 1) * 64, wn = (wave & 1) * 64;

  int seg = (lane & 3) ^ ((lane >> 3) & 3);
  const uint16_t* agl = A + (size_t)(m0 + wave * 32 + (lane >> 2)) * DIM + seg * 8;
  const uint16_t* bgl = W + (size_t)(n0 + wave * 32 + (lane >> 2)) * DIM + seg * 8;
  int lb = wave * 1024;             // uint16 idx; second call adds 512
  int ck = (lr >> 1) & 3;

  v4f acc[4][4];
  v4f vz = {0.f, 0.f, 0.f, 0.f};
  #pragma unroll
  for (int i = 0; i < 4; i++)
    #pragma unroll
    for (int j = 0; j < 4; j++) acc[i][j] = vz;

  // prologue: stage k0=0 into buf 0
  gl16(agl,            &As[0][lb]);
  gl16(agl + 16 * DIM, &As[0][lb + 512]);
  gl16(bgl,            &Bs[0][lb]);
  gl16(bgl + 16 * DIM, &Bs[0][lb + 512]);
  pipe_sync();

  int cur = 0;
  const int NT = DIM / 32;   // 24
  for (int t = 0; t < NT; ++t) {
    if (t + 1 < NT) {
      int kn = (t + 1) * 32;
      gl16(agl + kn,            &As[cur ^ 1][lb]);
      gl16(agl + kn + 16 * DIM, &As[cur ^ 1][lb + 512]);
      gl16(bgl + kn,            &Bs[cur ^ 1][lb]);
      gl16(bgl + kn + 16 * DIM, &Bs[cur ^ 1][lb + 512]);
    }
    v8s af[4], bfr[4];
    #pragma unroll
    for (int i = 0; i < 4; i++)
      af[i] = *(const v8s*)&As[cur][(wm + i * 16 + lr) * 32 + ((quad ^ ck) << 3)];
    #pragma unroll
    for (int j = 0; j < 4; j++)
      bfr[j] = *(const v8s*)&Bs[cur][(wn + j * 16 + lr) * 32 + ((quad ^ ck) << 3)];
    #pragma unroll
    for (int i = 0; i < 4; i++)
      #pragma unroll
      for (int j = 0; j < 4; j++)
        acc[i][j] = __builtin_amdgcn_mfma_f32_16x16x32_bf16(af[i], bfr[j], acc[i][j], 0, 0, 0);
    if (t + 1 < NT) pipe_sync();
    cur ^= 1;
  }

  float bj[4];
  #pragma unroll
  for (int j = 0; j < 4; j++) bj[j] = bias[n0 + wn + j * 16 + lr];

  if (mode == 2) {
    // Vw f16 [b,h,d,s]: within each 64-kk group, pos = pair*32+quadk*8+(nt&1)*4+j,
    // then 16B-chunk XOR-swizzled by d&7.  (kk = s&63; j==r since s0 is 4-aligned.)
    #pragma unroll
    for (int i = 0; i < 4; i++) {
      int m = m0 + wm + i * 16 + quad * 4;
      int b = m >> 11, s0 = m & 2047;
      int kk0 = s0 & 63;
      int pos = (kk0 >> 5) * 32 + ((kk0 >> 2) & 3) * 8 + ((kk0 >> 4) & 1) * 4;
      int chunk = pos >> 3, off = pos & 7;
      #pragma unroll
      for (int j = 0; j < 4; j++) {
        int n = n0 + wn + j * 16 + lr;
        int h = n >> 6, d = n & 63;
        uint2 pk;
        pk.x = pack_f16(acc[i][j][0] + bj[j], acc[i][j][1] + bj[j]);
        pk.y = pack_f16(acc[i][j][2] + bj[j], acc[i][j][3] + bj[j]);
        int idx = (s0 & ~63) + ((chunk ^ (d & 7)) << 3) + off;
        *(uint2*)&Vw[((size_t)(b * NH + h) * HD + d) * SEQ + idx] = pk;
      }
    }
  } else {
    uint16_t* Dst = (mode == 0) ? Qw : Kw;
    float scale = (mode == 0) ? 0.18033688f : 1.0f;   // HD^-0.5 * log2(e) folded into Q
    #pragma unroll
    for (int i = 0; i < 4; i++) {
      int m = m0 + wm + i * 16 + quad * 4;
      int b = m >> 11, s0 = m & 2047;
      #pragma unroll
      for (int j = 0; j < 4; j++) {
        int n = n0 + wn + j * 16 + lr;
        int h = n >> 6, d = n & 63;
        #pragma unroll
        for (int r = 0; r < 4; r++) {
          float v = (acc[i][j][r] + bj[j]) * scale;
          int s = s0 + r;
          int dd = (mode == 1) ? ((((d >> 3) ^ (s & 7)) << 3) + (d & 7)) : d;
          Dst[((size_t)(b * NH + h) * SEQ + s) * HD + dd] = f2bf(v);
        }
      }
    }
  }
}

// ---------------- O-projection GEMM: BM=64 x BN=128 tile (R13, neutral-kept) ----
__global__ __launch_bounds__(256) void gemm64_kernel(
    const uint16_t* __restrict__ AO, const uint16_t* __restrict__ WT,
    const float* __restrict__ bo, float* __restrict__ Out)
{
  __shared__ alignas(16) uint16_t As[2][64 * 32];
  __shared__ alignas(16) uint16_t Bs[2][128 * 32];
  const uint16_t* W = WT + (size_t)3 * DIM * DIM;

  int m0 = blockIdx.x * 64, n0 = blockIdx.y * 128;
  int tid = threadIdx.x;
  int wave = tid >> 6, lane = tid & 63, lr = lane & 15, quad = lane >> 4;
  int wm = (wave >> 1) * 32, wn = (wave & 1) * 64;

  int seg = (lane & 3) ^ ((lane >> 3) & 3);
  const uint16_t* agl = AO + (size_t)(m0 + wave * 16 + (lane >> 2)) * DIM + seg * 8;
  const uint16_t* bgl = W  + (size_t)(n0 + wave * 32 + (lane >> 2)) * DIM + seg * 8;
  int lba = wave * 512;    // uint16 idx: 16 rows x 32 elems per wave
  int lbb = wave * 1024;   // uint16 idx: 32 rows; second call adds 512
  int ck = (lr >> 1) & 3;

  v4f acc[2][4];
  v4f vz = {0.f, 0.f, 0.f, 0.f};
  #pragma unroll
  for (int i = 0; i < 2; i++)
    #pragma unroll
    for (int j = 0; j < 4; j++) acc[i][j] = vz;

  // prologue: stage k0=0 into buf 0
  gl16(agl,            &As[0][lba]);
  gl16(bgl,            &Bs[0][lbb]);
  gl16(bgl + 16 * DIM, &Bs[0][lbb + 512]);
  pipe_sync();

  int cur = 0;
  const int NT = DIM / 32;   // 24
  for (int t = 0; t < NT; ++t) {
    if (t + 1 < NT) {
      int kn = (t + 1) * 32;
      gl16(agl + kn,            &As[cur ^ 1][lba]);
      gl16(bgl + kn,            &Bs[cur ^ 1][lbb]);
      gl16(bgl + kn + 16 * DIM, &Bs[cur ^ 1][lbb + 512]);
    }
    v8s af[2], bfr[4];
    #pragma unroll
    for (int i = 0; i < 2; i++)
      af[i] = *(const v8s*)&As[cur][(wm + i * 16 + lr) * 32 + ((quad ^ ck) << 3)];
    #pragma unroll
    for (int j = 0; j < 4; j++)
      bfr[j] = *(const v8s*)&Bs[cur][(wn + j * 16 + lr) * 32 + ((quad ^ ck) << 3)];
    #pragma unroll
    for (int i = 0; i < 2; i++)
      #pragma unroll
      for (int j = 0; j < 4; j++)
        acc[i][j] = __builtin_amdgcn_mfma_f32_16x16x32_bf16(af[i], bfr[j], acc[i][j], 0, 0, 0);
    if (t + 1 < NT) pipe_sync();
    cur ^= 1;
  }

  float bj[4];
  #pragma unroll
  for (int j = 0; j < 4; j++) bj[j] = bo[n0 + wn + j * 16 + lr];

  #pragma unroll
  for (int i = 0; i < 2; i++) {
    int m = m0 + wm + i * 16 + quad * 4;
    #pragma unroll
    for (int j = 0; j < 4; j++) {
      int n = n0 + wn + j * 16 + lr;
      #pragma unroll
      for (int r = 0; r < 4; r++)
        Out[(size_t)(m + r) * DIM + n] = acc[i][j][r] + bj[j];
    }
  }
}

// ---------------- flash attention: 3-buffer counted-vmcnt pipeline (T4) ---------
// 4 waves x 32 q/wave, 128-q block, KVBLK=64.  Body for tile T:
//   { vmcnt(6); s_barrier; sched_barrier; load mask(T+2); gl16 stage(T+2) ->
//     buf (T+2)%3; compute(T) }
// Each body issues exactly 6 vmem ops fenced by the asm memory-clobber barriers;
// vmcnt retires in-order, so vmcnt(6) completes body T-2's group (gl16(T)+mask(T))
// while body T-1's 6 stay in flight -> every DMA gets TWO compute phases and the
// barrier drains nothing.  Masks ping-pong A/B via unroll-2 (no copies -> no
// forced waits).  Overwrite hazard: stage(T+2) hits buf (T-1)%3, protected by the
// top-of-body barrier (all waves finished compute(T-1) before any stage).
// LDS 48 KB -> still exactly 3 blocks/CU.
#define FLASH_TILE(CUR, M0LO, M0HI, M1LO, M1HI)                                   \
  {                                                                               \
    v8h pf0[2], pf1[2];                                                           \
    _Pragma("unroll")                                                             \
    for (int p = 0; p < 2; p++) {                                                 \
      v4f sA0 = m8, sB0 = m8, sA1 = m8, sB1 = m8;                                 \
      __builtin_amdgcn_s_setprio(1);                                              \
      {                                                                           \
        int rowb = ((2 * p) * 16 + lr) << 6;                                      \
        v8s kf0 = *(const v8s*)&Ks[CUR][rowb + ((quad ^ swk) << 3)];              \
        v8s kf1 = *(const v8s*)&Ks[CUR][rowb + (((quad + 4) ^ swk) << 3)];        \
        sA0 = __builtin_amdgcn_mfma_f32_16x16x32_bf16(kf0, qf0a, sA0, 0, 0, 0);   \
        sA0 = __builtin_amdgcn_mfma_f32_16x16x32_bf16(kf1, qf0b, sA0, 0, 0, 0);   \
        sA1 = __builtin_amdgcn_mfma_f32_16x16x32_bf16(kf0, qf1a, sA1, 0, 0, 0);   \
        sA1 = __builtin_amdgcn_mfma_f32_16x16x32_bf16(kf1, qf1b, sA1, 0, 0, 0);   \
      }                                                                           \
      {                                                                           \
        int rowb = ((2 * p + 1) * 16 + lr) << 6;                                  \
        v8s kf0 = *(const v8s*)&Ks[CUR][rowb + ((quad ^ swk) << 3)];              \
        v8s kf1 = *(const v8s*)&Ks[CUR][rowb + (((quad + 4) ^ swk) << 3)];        \
        sB0 = __builtin_amdgcn_mfma_f32_16x16x32_bf16(kf0, qf0a, sB0, 0, 0, 0);   \
        sB0 = __builtin_amdgcn_mfma_f32_16x16x32_bf16(kf1, qf0b, sB0, 0, 0, 0);   \
        sB1 = __builtin_amdgcn_mfma_f32_16x16x32_bf16(kf0, qf1a, sB1, 0, 0, 0);   \
        sB1 = __builtin_amdgcn_mfma_f32_16x16x32_bf16(kf1, qf1b, sB1, 0, 0, 0);   \
      }                                                                           \
      __builtin_amdgcn_s_setprio(0);                                              \
      uint32_t w0 = p ? (M0HI) : (M0LO), w1 = p ? (M1HI) : (M1LO);                \
      uint32_t a0 = (w0 >> sh0) & 15u, b0 = (w0 >> (sh0 + 16)) & 15u;             \
      uint32_t a1 = (w1 >> sh0) & 15u, b1 = (w1 >> (sh0 + 16)) & 15u;             \
      float p0[8], p1[8];                                                         \
      _Pragma("unroll")                                                           \
      for (int r = 0; r < 4; r++) {                                               \
        float e0a = fexp2(sA0[r]), e0b = fexp2(sB0[r]);                           \
        float e1a = fexp2(sA1[r]), e1b = fexp2(sB1[r]);                           \
        p0[r]     = (a0 & (1u << r)) ? e0a : 0.0f;                                \
        p0[4 + r] = (b0 & (1u << r)) ? e0b : 0.0f;                                \
        p1[r]     = (a1 & (1u << r)) ? e1a : 0.0f;                                \
        p1[4 + r] = (b1 & (1u << r)) ? e1b : 0.0f;                                \
      }                                                                           \
      union { uint4 u; v8h h; } c0, c1;                                           \
      c0.u.x = pack_f16(p0[0], p0[1]); c0.u.y = pack_f16(p0[2], p0[3]);           \
      c0.u.z = pack_f16(p0[4], p0[5]); c0.u.w = pack_f16(p0[6], p0[7]);           \
      c1.u.x = pack_f16(p1[0], p1[1]); c1.u.y = pack_f16(p1[2], p1[3]);           \
      c1.u.z = pack_f16(p1[4], p1[5]); c1.u.w = pack_f16(p1[6], p1[7]);           \
      pf0[p] = c0.h;                                                              \
      pf1[p] = c1.h;                                                              \
    }                                                                             \
    __builtin_amdgcn_s_setprio(1);                                                \
    _Pragma("unroll")                                                             \
    for (int dt = 0; dt < 4; dt++) {                                              \
      int rowb = (dt * 16 + lr) << 6;                                             \
      _Pragma("unroll")                                                           \
      for (int p = 0; p < 2; p++) {                                               \
        v8h vv = *(const v8h*)&Vs[CUR][rowb + (((p * 4 + quad) ^ swk) << 3)];     \
        acc0[dt] = __builtin_amdgcn_mfma_f32_16x16x32_f16(vv, pf0[p], acc0[dt], 0, 0, 0); \
        acc1[dt] = __builtin_amdgcn_mfma_f32_16x16x32_f16(vv, pf1[p], acc1[dt], 0, 0, 0); \
      }                                                                           \
    }                                                                             \
    lacc0 = __builtin_amdgcn_mfma_f32_16x16x32_f16(ones, pf0[0], lacc0, 0, 0, 0); \
    lacc0 = __builtin_amdgcn_mfma_f32_16x16x32_f16(ones, pf0[1], lacc0, 0, 0, 0); \
    lacc1 = __builtin_amdgcn_mfma_f32_16x16x32_f16(ones, pf1[0], lacc1, 0, 0, 0); \
    lacc1 = __builtin_amdgcn_mfma_f32_16x16x32_f16(ones, pf1[1], lacc1, 0, 0, 0); \
    __builtin_amdgcn_s_setprio(0);                                                \
  }

#define FLASH_STAGE(T, MW0, MW1)                                                  \
  if ((T) + 2 < NT) {                                                             \
    MW0 = Mp0[(size_t)((T) + 2) * SEQ];                                           \
    MW1 = Mp1[(size_t)((T) + 2) * SEQ];                                           \
    int kn = ((T) + 2) * 64;                                                      \
    int nb = (cur == 0) ? 2 : cur - 1;  /* (cur+2)%3 */                           \
    gl16(kgl + (size_t)kn * HD,       &Ks[nb][lb]);                               \
    gl16(kgl + (size_t)(kn + 8) * HD, &Ks[nb][lb + 512]);                         \
    gl16(vgl + kn,                    &Vs[nb][lb]);                               \
    gl16(vgl + kn + (size_t)8 * SEQ,  &Vs[nb][lb + 512]);                         \
  }

__global__ __launch_bounds__(256, 3) void flash_kernel(
    const uint16_t* __restrict__ Qg, const uint16_t* __restrict__ Kg,
    const uint16_t* __restrict__ Vg, const unsigned long long* __restrict__ Mb,
    uint16_t* __restrict__ AO)
{
  __shared__ alignas(16) uint16_t Ks[3][64 * 64];   // 3 x 8 KB, swizzle baked in Kw
  __shared__ alignas(16) uint16_t Vs[3][64 * 64];   // 3 x 8 KB f16, baked in Vw

  int tid = threadIdx.x, wave = tid >> 6, lane = tid & 63, lr = lane & 15, quad = lane >> 4;

  // XCD swizzle: dispatch id d -> XCD d&7 (round-robin).  768 = 8 * 96.
  int d = blockIdx.x + (blockIdx.y << 4);
  int nid = (d & 7) * 96 + (d >> 3);
  int bh = nid >> 4;
  int q0 = (nid & 15) * 128;
  int b = bh / NH, h = bh - b * NH;

  const uint16_t* Qp = Qg + (size_t)bh * SEQ * HD;
  const uint16_t* Kp = Kg + (size_t)bh * SEQ * HD;
  const uint16_t* Vp = Vg + (size_t)bh * HD * SEQ;
  int qg0 = q0 + wave * 32 + lr;
  int qg1 = qg0 + 16;
  const unsigned long long* Mp0 = Mb + (size_t)b * 32 * SEQ + qg0;
  const unsigned long long* Mp1 = Mp0 + 16;

  int swk = lr & 7, sh0 = quad * 4;

  v8s qf0a = *(const v8s*)&Qp[(size_t)qg0 * HD + quad * 8];
  v8s qf0b = *(const v8s*)&Qp[(size_t)qg0 * HD + 32 + quad * 8];
  v8s qf1a = *(const v8s*)&Qp[(size_t)qg1 * HD + quad * 8];
  v8s qf1b = *(const v8s*)&Qp[(size_t)qg1 * HD + 32 + quad * 8];

  // DMA: 4 waves x 4 calls x 64 lanes x 16B = 16 KB per tile (K 8KB + V 8KB);
  // wave w stages K rows [16w,16w+16) and V rows [16w,16w+16).
  const uint16_t* kgl = Kp + ((size_t)(wave * 16 + (lane >> 3)) * HD + (lane & 7) * 8);
  const uint16_t* vgl = Vp + ((size_t)(wave * 16 + (lane >> 3)) * SEQ + (lane & 7) * 8);
  int lb = wave * 1024;   // uint16 idx: 16 rows x 64 elems per wave

  v8h ones;
  #pragma unroll
  for (int i = 0; i < 8; i++) ones[i] = (_Float16)1.0f;

  v4f acc0[4], acc1[4], lacc0, lacc1;
  v4f vz = {0.f, 0.f, 0.f, 0.f};
  v4f m8 = {-8.f, -8.f, -8.f, -8.f};
  #pragma unroll
  for (int dt = 0; dt < 4; dt++) { acc0[dt] = vz; acc1[dt] = vz; }
  lacc0 = vz; lacc1 = vz;

  const int NT = SEQ / 64;   // 32 (even; unroll-2 clean)

  // prologue: issue {mask(0), gl16(0)} then {mask(1), gl16(1)} as two fenced
  // groups so the first body's vmcnt(6) covers exactly tile 0's group.
  unsigned long long mwA0 = Mp0[0];
  unsigned long long mwA1 = Mp1[0];
  gl16(kgl,                    &Ks[0][lb]);
  gl16(kgl + (size_t)8 * HD,   &Ks[0][lb + 512]);
  gl16(vgl,                    &Vs[0][lb]);
  gl16(vgl + (size_t)8 * SEQ,  &Vs[0][lb + 512]);
  __builtin_amdgcn_sched_barrier(0);
  unsigned long long mwB0 = Mp0[SEQ];
  unsigned long long mwB1 = Mp1[SEQ];
  gl16(kgl + (size_t)64 * HD,       &Ks[1][lb]);
  gl16(kgl + (size_t)(64 + 8) * HD, &Ks[1][lb + 512]);
  gl16(vgl + 64,                    &Vs[1][lb]);
  gl16(vgl + 64 + (size_t)8 * SEQ,  &Vs[1][lb + 512]);
  __builtin_amdgcn_sched_barrier(0);

  int cur = 0;
  for (int t2 = 0; t2 < NT; t2 += 2) {
    { // even body: tile t2, masks A
      asm volatile("s_waitcnt vmcnt(6)" ::: "memory");
      __builtin_amdgcn_s_barrier();
      __builtin_amdgcn_sched_barrier(0);
      uint32_t m0lo = (uint32_t)mwA0, m0hi = (uint32_t)(mwA0 >> 32);
      uint32_t m1lo = (uint32_t)mwA1, m1hi = (uint32_t)(mwA1 >> 32);
      FLASH_STAGE(t2, mwA0, mwA1);
      FLASH_TILE(cur, m0lo, m0hi, m1lo, m1hi);
      cur = (cur == 2) ? 0 : cur + 1;
    }
    { // odd body: tile t2+1, masks B
      if (t2 + 2 < NT) asm volatile("s_waitcnt vmcnt(6)" ::: "memory");
      else             asm volatile("s_waitcnt vmcnt(0)" ::: "memory");
      __builtin_amdgcn_s_barrier();
      __builtin_amdgcn_sched_barrier(0);
      uint32_t m0lo = (uint32_t)mwB0, m0hi = (uint32_t)(mwB0 >> 32);
      uint32_t m1lo = (uint32_t)mwB1, m1hi = (uint32_t)(mwB1 >> 32);
      FLASH_STAGE(t2 + 1, mwB0, mwB1);
      FLASH_TILE(cur, m0lo, m0hi, m1lo, m1hi);
      cur = (cur == 2) ? 0 : cur + 1;
    }
  }

  float ri0 = 1.0f / lacc0[0];
  float ri1 = 1.0f / lacc1[0];

  #pragma unroll
  for (int dt = 0; dt < 4; dt++) {
    uint2 pk;
    pk.x = pack_bf16(acc0[dt][0] * ri0, acc0[dt][1] * ri0);
    pk.y = pack_bf16(acc0[dt][2] * ri0, acc0[dt][3] * ri0);
    *(uint2*)&AO[(size_t)(b * SEQ + qg0) * DIM + h * HD + dt * 16 + sh0] = pk;
    pk.x = pack_bf16(acc1[dt][0] * ri1, acc1[dt][1] * ri1);
    pk.y = pack_bf16(acc1[dt][2] * ri1, acc1[dt][3] * ri1);
    *(uint2*)&AO[(size_t)(b * SEQ + qg1) * DIM + h * HD + dt * 16 + sh0] = pk;
  }
}

// ---------------- launch ----------------
extern "C" void kernel_launch(void* const* d_in, const int* in_sizes, int n_in,
                              void* d_out, int out_size, void* d_ws, size_t ws_size,
                              hipStream_t stream) {
  const float* from_t = (const float*)d_in[0];
  const float* to_t   = (const float*)d_in[1];
  const int*   maski  = (const int*)d_in[2];
  const float* Wq = (const float*)d_in[3];  const float* bq = (const float*)d_in[4];
  const float* Wk = (const float*)d_in[5];  const float* bk = (const float*)d_in[6];
  const float* Wv = (const float*)d_in[7];  const float* bv = (const float*)d_in[8];
  const float* Wo = (const float*)d_in[9];  const float* bo = (const float*)d_in[10];

  char* ws = (char*)d_ws;
  size_t off = 0;
  uint16_t* Xf = (uint16_t*)(ws + off); off += (size_t)MROWS * DIM * 2;
  uint16_t* Xt = (uint16_t*)(ws + off); off += (size_t)MROWS * DIM * 2;
  uint16_t* WT = (uint16_t*)(ws + off); off += (size_t)4 * DIM * DIM * 2;
  unsigned long long* Mbits = (unsigned long long*)(ws + off);
  off += (size_t)BSZ * 32 * SEQ * 8;                                    // 2 MB
  uint16_t* Qw = (uint16_t*)(ws + off); off += (size_t)MROWS * DIM * 2; // [b,h,s,d] bf16
  uint16_t* Kw = (uint16_t*)(ws + off); off += (size_t)MROWS * DIM * 2; // [b,h,s,d] bf16 swz
  uint16_t* Vw = (uint16_t*)(ws + off); off += (size_t)MROWS * DIM * 2; // [b,h,d,s] f16 perm+swz
  uint16_t* AO = (uint16_t*)(ws + off); off += (size_t)MROWS * DIM * 2; // [m,768] bf16
  float* Out = (float*)d_out;

  prepass_kernel<<<CVT_BLKS + WT_BLKS + MASK_BLKS, 256, 0, stream>>>(
      from_t, to_t, Xf, Xt, Wq, Wk, Wv, Wo, WT, maski, Mbits);

  gemm_kernel<<<dim3(64, 6, 3), 256, 0, stream>>>(Xf, Xt, WT, bq, bk, bv,
                                                  Qw, Kw, Vw);
  flash_kernel<<<dim3(SEQ / 128, BSZ * NH), 256, 0, stream>>>(Qw, Kw, Vw, Mbits, AO);
  gemm64_kernel<<<dim3(128, 6), 256, 0, stream>>>(AO, WT, bo, Out);
}